// Round 5
// baseline (356.275 us; speedup 1.0000x reference)
//
#include <hip/hip_runtime.h>

#define INC 5
#define H1C 16
#define H2C 32
#define KCL 256

// fallback (rescan) params
#define NBINS 40
#define BINSZ 2500
#define MAXCHUNK 12

// partition params
#define PB_SHIFT 9
#define PB_SZ 512               // nodes per bin
#define PB_NBMAX 256
#define PB_C 18432              // bucket capacity per bin (mean 16384 + 16 sigma)
#define PB_M 6144               // edges per partition block
#define PB_ETPB 6               // PB_M / 1024
#define PB_S 2                  // phase-2 sub-splits per bin

#define POOL_NB_MAX 1024

// ---------------------------------------------------------------------------
// Detect whether edge_index is int64 (odd 32-bit words all zero) or int32.
__global__ void k_detect(const unsigned int* __restrict__ ei, int* __restrict__ flag) {
    if (blockIdx.x == 0 && threadIdx.x == 0) {
        int is64 = 1;
        for (int i = 1; i < 32; i += 2)
            if (ei[i] != 0u) is64 = 0;
        *flag = is64;
    }
}

__global__ void k_init(unsigned* __restrict__ gcur, int nb) {
    int b = blockIdx.x * blockDim.x + threadIdx.x;
    if (b < nb) gcur[b] = (unsigned)b * PB_C;
}

// ---------------------------------------------------------------------------
// Phase 1: partition edges into dst-bins (LDS histogram + counting sort +
// coalesced bucket writes of packed entries src<<9 | dst&511).
__global__ __launch_bounds__(1024) void k_part(const unsigned int* __restrict__ ei,
                                               const int* __restrict__ flag,
                                               unsigned* __restrict__ gcur,
                                               unsigned* __restrict__ bucket,
                                               int E, int NB) {
    __shared__ int hist[PB_NBMAX];
    __shared__ int lbase[PB_NBMAX];
    __shared__ unsigned gbase[PB_NBMAX];
    __shared__ int sc[PB_NBMAX];
    __shared__ unsigned sorted[PB_M];
    __shared__ unsigned char sbin[PB_M];

    const int tid = threadIdx.x;
    const int e0 = blockIdx.x * PB_M;
    int m = E - e0; if (m > PB_M) m = PB_M;

    for (int i = tid; i < PB_NBMAX; i += 1024) hist[i] = 0;
    __syncthreads();

    const int is64 = *flag;  // uniform
    unsigned ee[PB_ETPB]; int eb[PB_ETPB]; int er[PB_ETPB];

#pragma unroll
    for (int ii = 0; ii < PB_ETPB; ii++) {
        const int off = tid + ii * 1024;
        eb[ii] = -1; ee[ii] = 0u; er[ii] = 0;
        if (off < m) {
            const int e = e0 + off;
            unsigned d, s;
            if (is64) { d = ei[2 * ((size_t)E + (size_t)e)]; s = ei[2 * (size_t)e]; }
            else      { d = ei[(size_t)E + (size_t)e];       s = ei[(size_t)e]; }
            const int b = (int)(d >> PB_SHIFT);
            eb[ii] = b;
            ee[ii] = (s << PB_SHIFT) | (d & (PB_SZ - 1));
            er[ii] = atomicAdd(&hist[b], 1);
        }
    }
    __syncthreads();

    // inclusive scan of hist (256 entries, Hillis-Steele)
    if (tid < PB_NBMAX) sc[tid] = hist[tid];
    __syncthreads();
    for (int st = 1; st < PB_NBMAX; st <<= 1) {
        int v = 0;
        if (tid < PB_NBMAX && tid >= st) v = sc[tid - st];
        __syncthreads();
        if (tid < PB_NBMAX) sc[tid] += v;
        __syncthreads();
    }
    if (tid < PB_NBMAX) lbase[tid] = sc[tid] - hist[tid];
    if (tid < NB) gbase[tid] = atomicAdd(&gcur[tid], (unsigned)hist[tid]);
    __syncthreads();

#pragma unroll
    for (int ii = 0; ii < PB_ETPB; ii++) {
        if (eb[ii] >= 0) {
            const int j = lbase[eb[ii]] + er[ii];
            sorted[j] = ee[ii];
            sbin[j] = (unsigned char)eb[ii];
        }
    }
    __syncthreads();

    for (int j = tid; j < m; j += 1024) {
        const int b = (int)sbin[j];
        const unsigned g = gbase[b] + (unsigned)(j - lbase[b]);
        if (g < (unsigned)(b + 1) * PB_C) bucket[g] = sorted[j];  // overflow guard
    }
}

// ---------------------------------------------------------------------------
// Phase 2: per (bin, sub): scan bucket slice densely, accumulate into LDS.
__global__ __launch_bounds__(1024) void k_gather(const unsigned* __restrict__ bucket,
                                                 const unsigned* __restrict__ gcur,
                                                 const float* __restrict__ x,
                                                 float* __restrict__ part,
                                                 int N, int NB) {
    __shared__ float acc[PB_SZ * 6];
    const int b = blockIdx.x / PB_S;
    const int sub = blockIdx.x % PB_S;
    const int tid = threadIdx.x;
    const int lo = b << PB_SHIFT;
    int hi = lo + PB_SZ; if (hi > N) hi = N;
    const int nloc = hi - lo;

    for (int i = tid; i < PB_SZ * 6; i += 1024) acc[i] = 0.0f;
    __syncthreads();

    int cnt = (int)(gcur[b] - (unsigned)b * PB_C);
    if (cnt > PB_C) cnt = PB_C;
    const int i0 = (cnt * sub) / PB_S;
    const int i1 = (cnt * (sub + 1)) / PB_S;
    const unsigned* bk = bucket + (size_t)b * PB_C;
    for (int i = i0 + tid; i < i1; i += 1024) {
        const unsigned e = bk[i];
        const unsigned s = e >> PB_SHIFT;
        const int dl = (int)(e & (PB_SZ - 1));
        const float* xr = x + (size_t)s * INC;
        float* a = acc + dl * 6;
        atomicAdd(a + 0, xr[0]);
        atomicAdd(a + 1, xr[1]);
        atomicAdd(a + 2, xr[2]);
        atomicAdd(a + 3, xr[3]);
        atomicAdd(a + 4, xr[4]);
        atomicAdd(a + 5, 1.0f);
    }
    __syncthreads();
    float* o = part + (size_t)sub * ((size_t)N * 6) + (size_t)lo * 6;
    for (int i = tid; i < nloc * 6; i += 1024) o[i] = acc[i];
}

// ---------------------------------------------------------------------------
// Fallback binned-rescan edge kernel.
__global__ __launch_bounds__(1024) void k_edge_bin(const unsigned int* __restrict__ ei,
                                                   const float* __restrict__ x,
                                                   const int* __restrict__ flag,
                                                   float* __restrict__ part,
                                                   int E, int nchunk, int N) {
    __shared__ float acc[BINSZ * 6];
    const int bin = blockIdx.x % NBINS;
    const int chunk = blockIdx.x / NBINS;
    const int lo = bin * BINSZ;
    const int hi = (lo + BINSZ < N) ? (lo + BINSZ) : N;
    const int nloc = hi - lo;
    for (int i = threadIdx.x; i < nloc * 6; i += 1024) acc[i] = 0.0f;
    __syncthreads();

    const int is64 = *flag;
    const long long ce = ((long long)E + nchunk - 1) / nchunk;
    const long long e0 = (long long)chunk * ce;
    long long e1 = e0 + ce;
    if (e1 > E) e1 = E;

    for (long long e = e0 + threadIdx.x; e < e1; e += 1024) {
        const int d = is64 ? (int)ei[2 * ((size_t)E + (size_t)e)] : (int)ei[(size_t)E + (size_t)e];
        if (d >= lo && d < hi) {
            const int s = is64 ? (int)ei[2 * (size_t)e] : (int)ei[(size_t)e];
            const float* xr = x + (size_t)s * INC;
            float* a = acc + (d - lo) * 6;
            atomicAdd(a + 0, xr[0]);
            atomicAdd(a + 1, xr[1]);
            atomicAdd(a + 2, xr[2]);
            atomicAdd(a + 3, xr[3]);
            atomicAdd(a + 4, xr[4]);
            atomicAdd(a + 5, 1.0f);
        }
    }
    __syncthreads();
    float* o = part + (size_t)chunk * ((size_t)N * 6) + (size_t)lo * 6;
    for (int i = threadIdx.x; i < nloc * 6; i += 1024) o[i] = acc[i];
}

// ---------------------------------------------------------------------------
// Reduce partials + node update.
__global__ void k_node2(const float* __restrict__ x, const float* __restrict__ part,
                        const float* __restrict__ W1, const float* __restrict__ root1,
                        const float* __restrict__ b1, float* __restrict__ h,
                        int N, int nchunk) {
    int n = blockIdx.x * blockDim.x + threadIdx.x;
    if (n >= N) return;
    float s[6] = {0.f, 0.f, 0.f, 0.f, 0.f, 0.f};
    for (int c = 0; c < nchunk; c++) {
        const float* p = part + (size_t)c * ((size_t)N * 6) + (size_t)n * 6;
#pragma unroll
        for (int j = 0; j < 6; j++) s[j] += p[j];
    }
    const float inv = 1.0f / fmaxf(s[5], 1.0f);
    float xs[INC], xv[INC];
#pragma unroll
    for (int c = 0; c < INC; c++) {
        xs[c] = s[c] * inv;
        xv[c] = x[(size_t)n * INC + c];
    }
    float hv[H1C];
#pragma unroll
    for (int j = 0; j < H1C; j++) {
        float v = b1[j];
#pragma unroll
        for (int c = 0; c < INC; c++)
            v = fmaf(xs[c], W1[c * H1C + j], fmaf(xv[c], root1[c * H1C + j], v));
        hv[j] = fmaxf(v, 0.0f);  // relu(leaky(relu(v))) == relu(v)
    }
    float4* hp = (float4*)(h + (size_t)n * H1C);
#pragma unroll
    for (int q = 0; q < 4; q++)
        hp[q] = make_float4(hv[4 * q], hv[4 * q + 1], hv[4 * q + 2], hv[4 * q + 3]);
}

// ---------------------------------------------------------------------------
// Pooling GEMM, float4-per-lane layout: lane l owns pos columns 4l..4l+3, so
// one wave covers a full 256-col row with ONE coalesced 1KB float4 load.
// 4 waves/block stride the node range; cross-wave reduce via padded-LDS
// atomics (4-way contention on 4096 distinct addresses).
__global__ __launch_bounds__(256) void k_pool(const float* __restrict__ pos,
                                              const float* __restrict__ h,
                                              float* __restrict__ xp_part, int N, int nb) {
    __shared__ float red[KCL * 17];
    const int tid = threadIdx.x;
    const int l = tid & 63;          // lane -> k-quad
    const int w = tid >> 6;          // wave -> node sub-stream (0..3)
    const int chunk = (N + nb - 1) / nb;
    const int n0 = blockIdx.x * chunk;
    const int n1 = min(n0 + chunk, N);

    float acc[4][H1C];
#pragma unroll
    for (int kk = 0; kk < 4; kk++)
#pragma unroll
        for (int j = 0; j < H1C; j++) acc[kk][j] = 0.0f;

    const float4* pos4 = (const float4*)pos;   // row stride = 64 float4

#pragma unroll 2
    for (int n = n0 + w; n < n1; n += 4) {
        const float4 p = pos4[(size_t)n * 64 + l];
        const float4* hr = (const float4*)(h + (size_t)n * H1C);
        const float4 h0 = hr[0], h1 = hr[1], h2 = hr[2], h3 = hr[3];
        const float hv[H1C] = {h0.x, h0.y, h0.z, h0.w, h1.x, h1.y, h1.z, h1.w,
                               h2.x, h2.y, h2.z, h2.w, h3.x, h3.y, h3.z, h3.w};
        const float pk[4] = {p.x, p.y, p.z, p.w};
#pragma unroll
        for (int kk = 0; kk < 4; kk++)
#pragma unroll
            for (int j = 0; j < H1C; j++)
                acc[kk][j] = fmaf(pk[kk], hv[j], acc[kk][j]);
    }

    for (int i = tid; i < KCL * 17; i += 256) red[i] = 0.0f;
    __syncthreads();
#pragma unroll
    for (int kk = 0; kk < 4; kk++)
#pragma unroll
        for (int j = 0; j < H1C; j++)
            atomicAdd(&red[(4 * l + kk) * 17 + j], acc[kk][j]);
    __syncthreads();
    float* o = xp_part + (size_t)blockIdx.x * (KCL * H1C);
    for (int i = tid; i < KCL * H1C; i += 256) o[i] = red[(i >> 4) * 17 + (i & 15)];
}

// ---------------------------------------------------------------------------
__global__ __launch_bounds__(1024) void k_xpred(const float* __restrict__ xp_part,
                                                float* __restrict__ xp, int nb) {
    __shared__ float r[1024];
    const int li = threadIdx.x & 255;
    const int sub = threadIdx.x >> 8;
    const int i = blockIdx.x * 256 + li;
    float s = 0.0f;
    for (int b = sub; b < nb; b += 4) s += xp_part[(size_t)b * (KCL * H1C) + i];
    r[threadIdx.x] = s;
    __syncthreads();
    if (threadIdx.x < 256)
        xp[blockIdx.x * 256 + threadIdx.x] =
            r[threadIdx.x] + r[256 + threadIdx.x] + r[512 + threadIdx.x] + r[768 + threadIdx.x];
}

// ---------------------------------------------------------------------------
// Tail: adj strictly positive => mask all-ones, deg2 = 256.
// Column sums via register butterfly (__shfl_xor).
__global__ __launch_bounds__(256) void k_tail(const float* __restrict__ xp,
                                              const float* __restrict__ W2,
                                              const float* __restrict__ root2,
                                              const float* __restrict__ b2,
                                              const float* __restrict__ lw1,
                                              const float* __restrict__ lb1,
                                              const float* __restrict__ lw2,
                                              const float* __restrict__ lb2,
                                              float* __restrict__ out) {
    __shared__ float red[4][H2C];
    __shared__ float bcast[H2C];
    const int t = threadIdx.x;
    const int wv = t >> 6;
    const int lane = t & 63;

    float row[H1C];
#pragma unroll
    for (int c = 0; c < H1C; c++) row[c] = xp[t * H1C + c];

    float v1[H2C];
#pragma unroll
    for (int j = 0; j < H2C; j++) {
        float v = 0.0f;
#pragma unroll
        for (int c = 0; c < H1C; c++) v = fmaf(row[c], W2[c * H2C + j], v);
        v1[j] = v;
    }
#pragma unroll
    for (int off = 1; off < 64; off <<= 1) {
#pragma unroll
        for (int j = 0; j < H2C; j++) v1[j] += __shfl_xor(v1[j], off);
    }
    if (lane == 0) {
#pragma unroll
        for (int j = 0; j < H2C; j++) red[wv][j] = v1[j];
    }
    __syncthreads();
    if (t < H2C) bcast[t] = red[0][t] + red[1][t] + red[2][t] + red[3][t];
    __syncthreads();

    float v2[H2C];
#pragma unroll
    for (int j = 0; j < H2C; j++) {
        float v = bcast[j] * (1.0f / KCL) + b2[j];
#pragma unroll
        for (int c = 0; c < H1C; c++) v = fmaf(row[c], root2[c * H2C + j], v);
        v2[j] = fmaxf(v, 0.0f);
    }
#pragma unroll
    for (int off = 1; off < 64; off <<= 1) {
#pragma unroll
        for (int j = 0; j < H2C; j++) v2[j] += __shfl_xor(v2[j], off);
    }
    if (lane == 0) {
#pragma unroll
        for (int j = 0; j < H2C; j++) red[wv][j] = v2[j];
    }
    __syncthreads();

    if (t == 0) {
        float g[H2C];
#pragma unroll
        for (int j = 0; j < H2C; j++)
            g[j] = (red[0][j] + red[1][j] + red[2][j] + red[3][j]) * (1.0f / KCL);
        float u[8];
#pragma unroll
        for (int a = 0; a < 8; a++) {
            float v = lb1[a];
#pragma unroll
            for (int j = 0; j < H2C; j++) v = fmaf(g[j], lw1[j * 8 + a], v);
            u[a] = v > 0.0f ? v : 0.1f * v;
        }
#pragma unroll
        for (int o = 0; o < 2; o++) {
            float v = lb2[o];
#pragma unroll
            for (int a = 0; a < 8; a++) v = fmaf(u[a], lw2[a * 2 + o], v);
            out[o] = v;
        }
    }
}

// ---------------------------------------------------------------------------
extern "C" void kernel_launch(void* const* d_in, const int* in_sizes, int n_in,
                              void* d_out, int out_size, void* d_ws, size_t ws_size,
                              hipStream_t stream) {
    const float* x         = (const float*)d_in[0];
    const unsigned int* ei = (const unsigned int*)d_in[1];
    // d_in[2] = edge_attr: unused (adj has no exact zeros -> mask all-ones)
    const float* pos   = (const float*)d_in[3];
    const float* W1    = (const float*)d_in[4];
    const float* root1 = (const float*)d_in[5];
    const float* b1    = (const float*)d_in[6];
    const float* W2    = (const float*)d_in[7];
    const float* root2 = (const float*)d_in[8];
    const float* b2    = (const float*)d_in[9];
    const float* lw1   = (const float*)d_in[10];
    const float* lb1   = (const float*)d_in[11];
    const float* lw2   = (const float*)d_in[12];
    const float* lb2   = (const float*)d_in[13];
    float* out = (float*)d_out;

    const int N = in_sizes[0] / INC;  // 100000
    const int E = in_sizes[1] / 2;    // 3200000
    const int NB = (N + PB_SZ - 1) >> PB_SHIFT;

    // workspace prefix (floats): [xp 4096][flag 16][h N*16][REGION ...]
    // REGION holds {part | bucket | gcur} during the edge phase, then is
    // REUSED for xp_part (dead data) during the pool phase.
    float* ws    = (float*)d_ws;
    float* xp    = ws;
    int*   flag  = (int*)(xp + KCL * H1C);
    float* h     = (float*)(flag + 16);
    float* regio = h + (size_t)N * H1C;

    const size_t pref_floats = (size_t)(KCL * H1C) + 16 + (size_t)N * H1C;
    const size_t region_floats = ws_size / 4 > pref_floats ? ws_size / 4 - pref_floats : 0;
    // fast path needs part[PB_S*N*6] + bucket[NB*PB_C] + gcur[256]
    const size_t fast_floats = (size_t)PB_S * N * 6 + (size_t)NB * PB_C + 256;

    // pool partial count: as many 4096-float slabs as fit in REGION, cap 1024
    int pool_nb = (int)(region_floats / (KCL * H1C));
    if (pool_nb > POOL_NB_MAX) pool_nb = POOL_NB_MAX;
    if (pool_nb < 1) pool_nb = 1;
    float* xp_part = regio;

    k_detect<<<1, 64, 0, stream>>>(ei, flag);

    if (region_floats >= fast_floats && N <= 131072 && NB <= PB_NBMAX) {
        // fast path: bucket partition + dense gather
        float* part      = regio;
        unsigned* bucket = (unsigned*)(part + (size_t)PB_S * N * 6);
        unsigned* gcur   = bucket + (size_t)NB * PB_C;
        const int P = (E + PB_M - 1) / PB_M;

        k_init<<<1, 256, 0, stream>>>(gcur, NB);
        k_part<<<P, 1024, 0, stream>>>(ei, flag, gcur, bucket, E, NB);
        k_gather<<<NB * PB_S, 1024, 0, stream>>>(bucket, gcur, x, part, N, NB);
        k_node2<<<(N + 255) / 256, 256, 0, stream>>>(x, part, W1, root1, b1, h, N, PB_S);
    } else {
        // fallback: binned rescan with as many chunks as fit
        int nchunk = (int)(region_floats / ((size_t)N * 6));
        if (nchunk > MAXCHUNK) nchunk = MAXCHUNK;
        if (nchunk < 1) nchunk = 1;
        float* part = regio;
        k_edge_bin<<<NBINS * nchunk, 1024, 0, stream>>>(ei, x, flag, part, E, nchunk, N);
        k_node2<<<(N + 255) / 256, 256, 0, stream>>>(x, part, W1, root1, b1, h, N, nchunk);
    }
    // xp_part reuses REGION (part/bucket are dead after k_node2)
    k_pool<<<pool_nb, 256, 0, stream>>>(pos, h, xp_part, N, pool_nb);
    k_xpred<<<16, 1024, 0, stream>>>(xp_part, xp, pool_nb);
    k_tail<<<1, 256, 0, stream>>>(xp, W2, root2, b2, lw1, lb1, lw2, lb2, out);
}

// Round 6
// 273.805 us; speedup vs baseline: 1.3012x; 1.3012x over previous
//
#include <hip/hip_runtime.h>

#define INC 5
#define H1C 16
#define H2C 32
#define KCL 256

// fallback (rescan) params
#define NBINS 40
#define BINSZ 2500
#define MAXCHUNK 12

// partition params
#define PB_SHIFT 9
#define PB_SZ 512               // nodes per bin
#define PB_NBMAX 256
#define PB_C 18432              // bucket capacity per bin (mean 16384 + 16 sigma)
#define PB_M 6144               // edges per partition block
#define PB_ETPB 6               // PB_M / 1024
#define PB_S 2                  // phase-2 sub-splits per bin

#define POOL_NB 512

// ---------------------------------------------------------------------------
// Detect whether edge_index is int64 (odd 32-bit words all zero) or int32.
__global__ void k_detect(const unsigned int* __restrict__ ei, int* __restrict__ flag) {
    if (blockIdx.x == 0 && threadIdx.x == 0) {
        int is64 = 1;
        for (int i = 1; i < 32; i += 2)
            if (ei[i] != 0u) is64 = 0;
        *flag = is64;
    }
}

__global__ void k_init(unsigned* __restrict__ gcur, int nb) {
    int b = blockIdx.x * blockDim.x + threadIdx.x;
    if (b < nb) gcur[b] = (unsigned)b * PB_C;
}

// ---------------------------------------------------------------------------
// Expand x rows (5 floats, 20B) into 32B-aligned 8-float rows so the edge
// gather needs 2 loads (float4 + float) instead of 5 scalar loads.
__global__ void k_prep(const float* __restrict__ x, float* __restrict__ x8, int N) {
    int n = blockIdx.x * blockDim.x + threadIdx.x;
    if (n >= N) return;
    const float* xr = x + (size_t)n * INC;
    float4* o = (float4*)(x8 + (size_t)n * 8);
    o[0] = make_float4(xr[0], xr[1], xr[2], xr[3]);
    o[1] = make_float4(xr[4], 0.0f, 0.0f, 0.0f);
}

// ---------------------------------------------------------------------------
// Phase 1: partition edges into dst-bins (LDS histogram + counting sort +
// coalesced bucket writes of packed entries src<<9 | dst&511).
__global__ __launch_bounds__(1024) void k_part(const unsigned int* __restrict__ ei,
                                               const int* __restrict__ flag,
                                               unsigned* __restrict__ gcur,
                                               unsigned* __restrict__ bucket,
                                               int E, int NB) {
    __shared__ int hist[PB_NBMAX];
    __shared__ int lbase[PB_NBMAX];
    __shared__ unsigned gbase[PB_NBMAX];
    __shared__ int sc[PB_NBMAX];
    __shared__ unsigned sorted[PB_M];
    __shared__ unsigned char sbin[PB_M];

    const int tid = threadIdx.x;
    const int e0 = blockIdx.x * PB_M;
    int m = E - e0; if (m > PB_M) m = PB_M;

    for (int i = tid; i < PB_NBMAX; i += 1024) hist[i] = 0;
    __syncthreads();

    const int is64 = *flag;  // uniform
    unsigned ee[PB_ETPB]; int eb[PB_ETPB]; int er[PB_ETPB];

#pragma unroll
    for (int ii = 0; ii < PB_ETPB; ii++) {
        const int off = tid + ii * 1024;
        eb[ii] = -1; ee[ii] = 0u; er[ii] = 0;
        if (off < m) {
            const int e = e0 + off;
            unsigned d, s;
            if (is64) { d = ei[2 * ((size_t)E + (size_t)e)]; s = ei[2 * (size_t)e]; }
            else      { d = ei[(size_t)E + (size_t)e];       s = ei[(size_t)e]; }
            const int b = (int)(d >> PB_SHIFT);
            eb[ii] = b;
            ee[ii] = (s << PB_SHIFT) | (d & (PB_SZ - 1));
            er[ii] = atomicAdd(&hist[b], 1);
        }
    }
    __syncthreads();

    // inclusive scan of hist (256 entries, Hillis-Steele)
    if (tid < PB_NBMAX) sc[tid] = hist[tid];
    __syncthreads();
    for (int st = 1; st < PB_NBMAX; st <<= 1) {
        int v = 0;
        if (tid < PB_NBMAX && tid >= st) v = sc[tid - st];
        __syncthreads();
        if (tid < PB_NBMAX) sc[tid] += v;
        __syncthreads();
    }
    if (tid < PB_NBMAX) lbase[tid] = sc[tid] - hist[tid];
    if (tid < NB) gbase[tid] = atomicAdd(&gcur[tid], (unsigned)hist[tid]);
    __syncthreads();

#pragma unroll
    for (int ii = 0; ii < PB_ETPB; ii++) {
        if (eb[ii] >= 0) {
            const int j = lbase[eb[ii]] + er[ii];
            sorted[j] = ee[ii];
            sbin[j] = (unsigned char)eb[ii];
        }
    }
    __syncthreads();

    for (int j = tid; j < m; j += 1024) {
        const int b = (int)sbin[j];
        const unsigned g = gbase[b] + (unsigned)(j - lbase[b]);
        if (g < (unsigned)(b + 1) * PB_C) bucket[g] = sorted[j];  // overflow guard
    }
}

// ---------------------------------------------------------------------------
// Phase 2: per (bin, sub): scan bucket slice densely, accumulate
// {x8[src][0..4], 1} into LDS for the bin's 512 nodes, write partial.
__global__ __launch_bounds__(1024) void k_gather(const unsigned* __restrict__ bucket,
                                                 const unsigned* __restrict__ gcur,
                                                 const float* __restrict__ x8,
                                                 float* __restrict__ part,
                                                 int N, int NB) {
    __shared__ float acc[PB_SZ * 6];
    const int b = blockIdx.x / PB_S;
    const int sub = blockIdx.x % PB_S;
    const int tid = threadIdx.x;
    const int lo = b << PB_SHIFT;
    int hi = lo + PB_SZ; if (hi > N) hi = N;
    const int nloc = hi - lo;

    for (int i = tid; i < PB_SZ * 6; i += 1024) acc[i] = 0.0f;
    __syncthreads();

    int cnt = (int)(gcur[b] - (unsigned)b * PB_C);
    if (cnt > PB_C) cnt = PB_C;
    const int i0 = (cnt * sub) / PB_S;
    const int i1 = (cnt * (sub + 1)) / PB_S;
    const unsigned* bk = bucket + (size_t)b * PB_C;
    for (int i = i0 + tid; i < i1; i += 1024) {
        const unsigned e = bk[i];
        const unsigned s = e >> PB_SHIFT;
        const int dl = (int)(e & (PB_SZ - 1));
        const float4 xr4 = *(const float4*)(x8 + (size_t)s * 8);
        const float xr5 = x8[(size_t)s * 8 + 4];
        float* a = acc + dl * 6;
        atomicAdd(a + 0, xr4.x);
        atomicAdd(a + 1, xr4.y);
        atomicAdd(a + 2, xr4.z);
        atomicAdd(a + 3, xr4.w);
        atomicAdd(a + 4, xr5);
        atomicAdd(a + 5, 1.0f);
    }
    __syncthreads();
    float* o = part + (size_t)sub * ((size_t)N * 6) + (size_t)lo * 6;
    for (int i = tid; i < nloc * 6; i += 1024) o[i] = acc[i];
}

// ---------------------------------------------------------------------------
// Fallback binned-rescan edge kernel.
__global__ __launch_bounds__(1024) void k_edge_bin(const unsigned int* __restrict__ ei,
                                                   const float* __restrict__ x,
                                                   const int* __restrict__ flag,
                                                   float* __restrict__ part,
                                                   int E, int nchunk, int N) {
    __shared__ float acc[BINSZ * 6];
    const int bin = blockIdx.x % NBINS;
    const int chunk = blockIdx.x / NBINS;
    const int lo = bin * BINSZ;
    const int hi = (lo + BINSZ < N) ? (lo + BINSZ) : N;
    const int nloc = hi - lo;
    for (int i = threadIdx.x; i < nloc * 6; i += 1024) acc[i] = 0.0f;
    __syncthreads();

    const int is64 = *flag;
    const long long ce = ((long long)E + nchunk - 1) / nchunk;
    const long long e0 = (long long)chunk * ce;
    long long e1 = e0 + ce;
    if (e1 > E) e1 = E;

    for (long long e = e0 + threadIdx.x; e < e1; e += 1024) {
        const int d = is64 ? (int)ei[2 * ((size_t)E + (size_t)e)] : (int)ei[(size_t)E + (size_t)e];
        if (d >= lo && d < hi) {
            const int s = is64 ? (int)ei[2 * (size_t)e] : (int)ei[(size_t)e];
            const float* xr = x + (size_t)s * INC;
            float* a = acc + (d - lo) * 6;
            atomicAdd(a + 0, xr[0]);
            atomicAdd(a + 1, xr[1]);
            atomicAdd(a + 2, xr[2]);
            atomicAdd(a + 3, xr[3]);
            atomicAdd(a + 4, xr[4]);
            atomicAdd(a + 5, 1.0f);
        }
    }
    __syncthreads();
    float* o = part + (size_t)chunk * ((size_t)N * 6) + (size_t)lo * 6;
    for (int i = threadIdx.x; i < nloc * 6; i += 1024) o[i] = acc[i];
}

// ---------------------------------------------------------------------------
// Reduce partials + node update.
__global__ void k_node2(const float* __restrict__ x, const float* __restrict__ part,
                        const float* __restrict__ W1, const float* __restrict__ root1,
                        const float* __restrict__ b1, float* __restrict__ h,
                        int N, int nchunk) {
    int n = blockIdx.x * blockDim.x + threadIdx.x;
    if (n >= N) return;
    float s[6] = {0.f, 0.f, 0.f, 0.f, 0.f, 0.f};
    for (int c = 0; c < nchunk; c++) {
        const float* p = part + (size_t)c * ((size_t)N * 6) + (size_t)n * 6;
#pragma unroll
        for (int j = 0; j < 6; j++) s[j] += p[j];
    }
    const float inv = 1.0f / fmaxf(s[5], 1.0f);
    float xs[INC], xv[INC];
#pragma unroll
    for (int c = 0; c < INC; c++) {
        xs[c] = s[c] * inv;
        xv[c] = x[(size_t)n * INC + c];
    }
    float hv[H1C];
#pragma unroll
    for (int j = 0; j < H1C; j++) {
        float v = b1[j];
#pragma unroll
        for (int c = 0; c < INC; c++)
            v = fmaf(xs[c], W1[c * H1C + j], fmaf(xv[c], root1[c * H1C + j], v));
        hv[j] = fmaxf(v, 0.0f);  // relu(leaky(relu(v))) == relu(v)
    }
    float4* hp = (float4*)(h + (size_t)n * H1C);
#pragma unroll
    for (int q = 0; q < 4; q++)
        hp[q] = make_float4(hv[4 * q], hv[4 * q + 1], hv[4 * q + 2], hv[4 * q + 3]);
}

// ---------------------------------------------------------------------------
// Pooling GEMM: lane owns a float2 of pos columns (cols 2c2, 2c2+1), so
// acc = 2x16 = 32 VGPR (no spill; launch_bounds(512,2) caps at 256 VGPR).
// 512 threads = 4 node streams x 128 col-pair lanes; unroll 4 gives 4
// independent 8B/lane (512B/wave) loads in flight. 512 blocks = 2/CU.
__global__ __launch_bounds__(512, 2) void k_pool(const float* __restrict__ pos,
                                                 const float* __restrict__ h,
                                                 float* __restrict__ xp_part, int N, int nb) {
    __shared__ float red[KCL * 17];
    const int tid = threadIdx.x;
    const int c2 = tid & 127;        // col pair
    const int w = tid >> 7;          // node sub-stream (0..3)
    const int chunk = (N + nb - 1) / nb;
    const int n0 = blockIdx.x * chunk;
    const int n1 = min(n0 + chunk, N);

    float acc0[H1C], acc1[H1C];
#pragma unroll
    for (int j = 0; j < H1C; j++) { acc0[j] = 0.0f; acc1[j] = 0.0f; }

    const float2* pos2 = (const float2*)pos;   // row stride = 128 float2

#pragma unroll 4
    for (int n = n0 + w; n < n1; n += 4) {
        const float2 p = pos2[(size_t)n * 128 + c2];
        const float4* hr = (const float4*)(h + (size_t)n * H1C);
        const float4 h0 = hr[0], h1 = hr[1], h2 = hr[2], h3 = hr[3];
        const float hv[H1C] = {h0.x, h0.y, h0.z, h0.w, h1.x, h1.y, h1.z, h1.w,
                               h2.x, h2.y, h2.z, h2.w, h3.x, h3.y, h3.z, h3.w};
#pragma unroll
        for (int j = 0; j < H1C; j++) {
            acc0[j] = fmaf(p.x, hv[j], acc0[j]);
            acc1[j] = fmaf(p.y, hv[j], acc1[j]);
        }
    }

    for (int i = tid; i < KCL * 17; i += 512) red[i] = 0.0f;
    __syncthreads();
#pragma unroll
    for (int j = 0; j < H1C; j++) {
        atomicAdd(&red[(2 * c2 + 0) * 17 + j], acc0[j]);   // 4-way contention max
        atomicAdd(&red[(2 * c2 + 1) * 17 + j], acc1[j]);
    }
    __syncthreads();
    float* o = xp_part + (size_t)blockIdx.x * (KCL * H1C);
    for (int i = tid; i < KCL * H1C; i += 512) o[i] = red[(i >> 4) * 17 + (i & 15)];
}

// ---------------------------------------------------------------------------
// xp[i] = sum_b xp_part[b][i]. 64 blocks x 1024 thr; 64 consecutive i per
// block (coalesced 256B/wave loads), 16 slab sub-streams, LDS tree reduce.
__global__ __launch_bounds__(1024) void k_xpred(const float* __restrict__ xp_part,
                                                float* __restrict__ xp, int nb) {
    __shared__ float r[1024];
    const int li = threadIdx.x & 63;
    const int sub = threadIdx.x >> 6;      // 0..15
    const int i = blockIdx.x * 64 + li;
    float s = 0.0f;
    for (int b = sub; b < nb; b += 16) s += xp_part[(size_t)b * (KCL * H1C) + i];
    r[threadIdx.x] = s;
    __syncthreads();
    if (threadIdx.x < 512) r[threadIdx.x] += r[threadIdx.x + 512];
    __syncthreads();
    if (threadIdx.x < 256) r[threadIdx.x] += r[threadIdx.x + 256];
    __syncthreads();
    if (threadIdx.x < 128) r[threadIdx.x] += r[threadIdx.x + 128];
    __syncthreads();
    if (threadIdx.x < 64) xp[i] = r[threadIdx.x] + r[threadIdx.x + 64];
}

// ---------------------------------------------------------------------------
// Tail: adj strictly positive => mask all-ones, deg2 = 256.
// Column sums via register butterfly (__shfl_xor).
__global__ __launch_bounds__(256) void k_tail(const float* __restrict__ xp,
                                              const float* __restrict__ W2,
                                              const float* __restrict__ root2,
                                              const float* __restrict__ b2,
                                              const float* __restrict__ lw1,
                                              const float* __restrict__ lb1,
                                              const float* __restrict__ lw2,
                                              const float* __restrict__ lb2,
                                              float* __restrict__ out) {
    __shared__ float red[4][H2C];
    __shared__ float bcast[H2C];
    const int t = threadIdx.x;
    const int wv = t >> 6;
    const int lane = t & 63;

    float row[H1C];
#pragma unroll
    for (int c = 0; c < H1C; c++) row[c] = xp[t * H1C + c];

    float v1[H2C];
#pragma unroll
    for (int j = 0; j < H2C; j++) {
        float v = 0.0f;
#pragma unroll
        for (int c = 0; c < H1C; c++) v = fmaf(row[c], W2[c * H2C + j], v);
        v1[j] = v;
    }
#pragma unroll
    for (int off = 1; off < 64; off <<= 1) {
#pragma unroll
        for (int j = 0; j < H2C; j++) v1[j] += __shfl_xor(v1[j], off);
    }
    if (lane == 0) {
#pragma unroll
        for (int j = 0; j < H2C; j++) red[wv][j] = v1[j];
    }
    __syncthreads();
    if (t < H2C) bcast[t] = red[0][t] + red[1][t] + red[2][t] + red[3][t];
    __syncthreads();

    float v2[H2C];
#pragma unroll
    for (int j = 0; j < H2C; j++) {
        float v = bcast[j] * (1.0f / KCL) + b2[j];
#pragma unroll
        for (int c = 0; c < H1C; c++) v = fmaf(row[c], root2[c * H2C + j], v);
        v2[j] = fmaxf(v, 0.0f);
    }
#pragma unroll
    for (int off = 1; off < 64; off <<= 1) {
#pragma unroll
        for (int j = 0; j < H2C; j++) v2[j] += __shfl_xor(v2[j], off);
    }
    if (lane == 0) {
#pragma unroll
        for (int j = 0; j < H2C; j++) red[wv][j] = v2[j];
    }
    __syncthreads();

    if (t == 0) {
        float g[H2C];
#pragma unroll
        for (int j = 0; j < H2C; j++)
            g[j] = (red[0][j] + red[1][j] + red[2][j] + red[3][j]) * (1.0f / KCL);
        float u[8];
#pragma unroll
        for (int a = 0; a < 8; a++) {
            float v = lb1[a];
#pragma unroll
            for (int j = 0; j < H2C; j++) v = fmaf(g[j], lw1[j * 8 + a], v);
            u[a] = v > 0.0f ? v : 0.1f * v;
        }
#pragma unroll
        for (int o = 0; o < 2; o++) {
            float v = lb2[o];
#pragma unroll
            for (int a = 0; a < 8; a++) v = fmaf(u[a], lw2[a * 2 + o], v);
            out[o] = v;
        }
    }
}

// ---------------------------------------------------------------------------
extern "C" void kernel_launch(void* const* d_in, const int* in_sizes, int n_in,
                              void* d_out, int out_size, void* d_ws, size_t ws_size,
                              hipStream_t stream) {
    const float* x         = (const float*)d_in[0];
    const unsigned int* ei = (const unsigned int*)d_in[1];
    // d_in[2] = edge_attr: unused (adj has no exact zeros -> mask all-ones)
    const float* pos   = (const float*)d_in[3];
    const float* W1    = (const float*)d_in[4];
    const float* root1 = (const float*)d_in[5];
    const float* b1    = (const float*)d_in[6];
    const float* W2    = (const float*)d_in[7];
    const float* root2 = (const float*)d_in[8];
    const float* b2    = (const float*)d_in[9];
    const float* lw1   = (const float*)d_in[10];
    const float* lb1   = (const float*)d_in[11];
    const float* lw2   = (const float*)d_in[12];
    const float* lb2   = (const float*)d_in[13];
    float* out = (float*)d_out;

    const int N = in_sizes[0] / INC;  // 100000
    const int E = in_sizes[1] / 2;    // 3200000
    const int NB = (N + PB_SZ - 1) >> PB_SHIFT;

    // workspace prefix (floats): [xp 4096][flag 16][h N*16][REGION ...]
    float* ws    = (float*)d_ws;
    float* xp    = ws;
    int*   flag  = (int*)(xp + KCL * H1C);
    float* h     = (float*)(flag + 16);
    float* regio = h + (size_t)N * H1C;

    const size_t pref_floats = (size_t)(KCL * H1C) + 16 + (size_t)N * H1C;
    const size_t region_floats = ws_size / 4 > pref_floats ? ws_size / 4 - pref_floats : 0;
    // fast path region: part[PB_S*N*6] | x8[N*8] | bucket[NB*PB_C] | gcur[256]
    const size_t fast_floats = (size_t)PB_S * N * 6 + (size_t)N * 8 + (size_t)NB * PB_C + 256;

    k_detect<<<1, 64, 0, stream>>>(ei, flag);

    if (region_floats >= fast_floats && N <= 131072 && NB <= PB_NBMAX) {
        float* part      = regio;
        float* x8        = part + (size_t)PB_S * N * 6;
        unsigned* bucket = (unsigned*)(x8 + (size_t)N * 8);
        unsigned* gcur   = bucket + (size_t)NB * PB_C;
        const int P = (E + PB_M - 1) / PB_M;

        k_init<<<1, 256, 0, stream>>>(gcur, NB);
        k_prep<<<(N + 255) / 256, 256, 0, stream>>>(x, x8, N);
        k_part<<<P, 1024, 0, stream>>>(ei, flag, gcur, bucket, E, NB);
        k_gather<<<NB * PB_S, 1024, 0, stream>>>(bucket, gcur, x8, part, N, NB);
        k_node2<<<(N + 255) / 256, 256, 0, stream>>>(x, part, W1, root1, b1, h, N, PB_S);

        // xp_part reuses x8/bucket space (dead after k_gather):
        // 512 slabs * 4096 floats = 2.1M < N*8 + NB*PB_C
        float* xp_part = x8;
        k_pool<<<POOL_NB, 512, 0, stream>>>(pos, h, xp_part, N, POOL_NB);
        k_xpred<<<64, 1024, 0, stream>>>(xp_part, xp, POOL_NB);
    } else {
        // fallback: binned rescan with as many chunks as fit (reserve pool slabs)
        size_t avail = region_floats > (size_t)POOL_NB * KCL * H1C
                     ? region_floats - (size_t)POOL_NB * KCL * H1C : 0;
        int nchunk = (int)(avail / ((size_t)N * 6));
        if (nchunk > MAXCHUNK) nchunk = MAXCHUNK;
        if (nchunk < 1) nchunk = 1;
        float* part = regio;
        float* xp_part = part + (size_t)nchunk * N * 6;
        k_edge_bin<<<NBINS * nchunk, 1024, 0, stream>>>(ei, x, flag, part, E, nchunk, N);
        k_node2<<<(N + 255) / 256, 256, 0, stream>>>(x, part, W1, root1, b1, h, N, nchunk);
        k_pool<<<POOL_NB, 512, 0, stream>>>(pos, h, xp_part, N, POOL_NB);
        k_xpred<<<64, 1024, 0, stream>>>(xp_part, xp, POOL_NB);
    }
    k_tail<<<1, 256, 0, stream>>>(xp, W2, root2, b2, lw1, lb1, lw2, lb2, out);
}

// Round 7
// 166.478 us; speedup vs baseline: 2.1401x; 1.6447x over previous
//
#include <hip/hip_runtime.h>

#define INC 5
#define H1C 16
#define H2C 32
#define KCL 256

// fallback (rescan) params
#define NBINS 40
#define BINSZ 2500
#define MAXCHUNK 12

// partition params
#define PB_SHIFT 9
#define PB_SZ 512               // nodes per bin
#define PB_NBMAX 256
#define PB_C 18432              // bucket capacity per bin (mean 16384 + 16 sigma)
#define PB_M 6144               // edges per partition block
#define PB_ETPB 6               // PB_M / 1024
#define PB_S 2                  // phase-2 sub-splits per bin
#define PB_GMAX 9216            // max entries per gather block = PB_C/PB_S
#define PB_GETG 9               // ceil(PB_GMAX/1024)

#define POOL_NB 512

// ---------------------------------------------------------------------------
// Fused setup: x8 expansion + gcur init + int64/int32 detect.
__global__ void k_setup(const float* __restrict__ x, float* __restrict__ x8,
                        const unsigned int* __restrict__ ei, int* __restrict__ flag,
                        unsigned* __restrict__ gcur, int N, int NB) {
    int n = blockIdx.x * blockDim.x + threadIdx.x;
    if (n < N) {
        const float* xr = x + (size_t)n * INC;
        float4* o = (float4*)(x8 + (size_t)n * 8);
        o[0] = make_float4(xr[0], xr[1], xr[2], xr[3]);
        o[1] = make_float4(xr[4], 0.0f, 0.0f, 0.0f);
    }
    if (blockIdx.x == 0) {
        if (threadIdx.x < (unsigned)NB) gcur[threadIdx.x] = (unsigned)threadIdx.x * PB_C;
        if (threadIdx.x == 0) {
            int is64 = 1;
            for (int i = 1; i < 32; i += 2)
                if (ei[i] != 0u) is64 = 0;
            *flag = is64;
        }
    }
}

// standalone detect for the fallback path
__global__ void k_detect(const unsigned int* __restrict__ ei, int* __restrict__ flag) {
    if (blockIdx.x == 0 && threadIdx.x == 0) {
        int is64 = 1;
        for (int i = 1; i < 32; i += 2)
            if (ei[i] != 0u) is64 = 0;
        *flag = is64;
    }
}

// ---------------------------------------------------------------------------
// Phase 1: partition edges into dst-bins (LDS histogram + counting sort +
// coalesced bucket writes of packed entries src<<9 | dst&511).
__global__ __launch_bounds__(1024) void k_part(const unsigned int* __restrict__ ei,
                                               const int* __restrict__ flag,
                                               unsigned* __restrict__ gcur,
                                               unsigned* __restrict__ bucket,
                                               int E, int NB) {
    __shared__ int hist[PB_NBMAX];
    __shared__ int lbase[PB_NBMAX];
    __shared__ unsigned gbase[PB_NBMAX];
    __shared__ int sc[PB_NBMAX];
    __shared__ unsigned sorted[PB_M];
    __shared__ unsigned char sbin[PB_M];

    const int tid = threadIdx.x;
    const int e0 = blockIdx.x * PB_M;
    int m = E - e0; if (m > PB_M) m = PB_M;

    for (int i = tid; i < PB_NBMAX; i += 1024) hist[i] = 0;
    __syncthreads();

    const int is64 = *flag;  // uniform
    unsigned ee[PB_ETPB]; int eb[PB_ETPB]; int er[PB_ETPB];

#pragma unroll
    for (int ii = 0; ii < PB_ETPB; ii++) {
        const int off = tid + ii * 1024;
        eb[ii] = -1; ee[ii] = 0u; er[ii] = 0;
        if (off < m) {
            const int e = e0 + off;
            unsigned d, s;
            if (is64) { d = ei[2 * ((size_t)E + (size_t)e)]; s = ei[2 * (size_t)e]; }
            else      { d = ei[(size_t)E + (size_t)e];       s = ei[(size_t)e]; }
            const int b = (int)(d >> PB_SHIFT);
            eb[ii] = b;
            ee[ii] = (s << PB_SHIFT) | (d & (PB_SZ - 1));
            er[ii] = atomicAdd(&hist[b], 1);
        }
    }
    __syncthreads();

    // inclusive scan of hist (256 entries, Hillis-Steele)
    if (tid < PB_NBMAX) sc[tid] = hist[tid];
    __syncthreads();
    for (int st = 1; st < PB_NBMAX; st <<= 1) {
        int v = 0;
        if (tid < PB_NBMAX && tid >= st) v = sc[tid - st];
        __syncthreads();
        if (tid < PB_NBMAX) sc[tid] += v;
        __syncthreads();
    }
    if (tid < PB_NBMAX) lbase[tid] = sc[tid] - hist[tid];
    if (tid < NB) gbase[tid] = atomicAdd(&gcur[tid], (unsigned)hist[tid]);
    __syncthreads();

#pragma unroll
    for (int ii = 0; ii < PB_ETPB; ii++) {
        if (eb[ii] >= 0) {
            const int j = lbase[eb[ii]] + er[ii];
            sorted[j] = ee[ii];
            sbin[j] = (unsigned char)eb[ii];
        }
    }
    __syncthreads();

    for (int j = tid; j < m; j += 1024) {
        const int b = (int)sbin[j];
        const unsigned g = gbase[b] + (unsigned)(j - lbase[b]);
        if (g < (unsigned)(b + 1) * PB_C) bucket[g] = sorted[j];  // overflow guard
    }
}

// ---------------------------------------------------------------------------
// Phase 2 (atomic-free accumulate): counting-sort the slice by local dst in
// LDS (1 u32 rank-atomic + 1 LDS write per edge), then thread t<512 owns node
// t's run 1st half / t>=512 the 2nd half, accumulating x8[src] in REGISTERS.
// Degree comes free from the histogram. No f32 atomics anywhere.
__global__ __launch_bounds__(1024) void k_gather(const unsigned* __restrict__ bucket,
                                                 const unsigned* __restrict__ gcur,
                                                 const float* __restrict__ x8,
                                                 float* __restrict__ part,
                                                 int N, int NB) {
    __shared__ unsigned sorted[PB_GMAX];   // 36 KB
    __shared__ int hist[PB_SZ];
    __shared__ int sc[PB_SZ];
    __shared__ int lbase[PB_SZ];
    __shared__ float stage[PB_SZ * 6];     // 12 KB

    const int b = blockIdx.x / PB_S;
    const int sub = blockIdx.x % PB_S;
    const int tid = threadIdx.x;
    const int lo = b << PB_SHIFT;
    int hi = lo + PB_SZ; if (hi > N) hi = N;
    const int nloc = hi - lo;

    int cnt = (int)(gcur[b] - (unsigned)b * PB_C);
    if (cnt > PB_C) cnt = PB_C;
    const int i0 = (cnt * sub) / PB_S;
    const int i1 = (cnt * (sub + 1)) / PB_S;
    const int m = i1 - i0;
    const unsigned* bk = bucket + (size_t)b * PB_C + i0;

    for (int i = tid; i < PB_SZ; i += 1024) hist[i] = 0;
    __syncthreads();

    unsigned ee[PB_GETG]; int edl[PB_GETG]; int er[PB_GETG];
#pragma unroll
    for (int ii = 0; ii < PB_GETG; ii++) {
        const int off = tid + ii * 1024;
        edl[ii] = -1; ee[ii] = 0u; er[ii] = 0;
        if (off < m) {
            const unsigned e = bk[off];
            const int dl = (int)(e & (PB_SZ - 1));
            edl[ii] = dl;
            ee[ii] = e;
            er[ii] = atomicAdd(&hist[dl], 1);
        }
    }
    __syncthreads();

    // exclusive scan of 512-entry hist
    if (tid < PB_SZ) sc[tid] = hist[tid];
    __syncthreads();
    for (int st = 1; st < PB_SZ; st <<= 1) {
        int v = 0;
        if (tid < PB_SZ && tid >= st) v = sc[tid - st];
        __syncthreads();
        if (tid < PB_SZ) sc[tid] += v;
        __syncthreads();
    }
    if (tid < PB_SZ) lbase[tid] = sc[tid] - hist[tid];
    __syncthreads();

#pragma unroll
    for (int ii = 0; ii < PB_GETG; ii++)
        if (edl[ii] >= 0) sorted[lbase[edl[ii]] + er[ii]] = ee[ii];
    __syncthreads();

    // register accumulation: 2 threads per node, half a run each
    const int node = tid & (PB_SZ - 1);
    const int half = tid >> PB_SHIFT;      // 0 or 1
    const int start = lbase[node];
    const int len = hist[node];
    const int js = start + (half ? (len >> 1) : 0);
    const int je = start + (half ? len : (len >> 1));
    float a0 = 0.f, a1 = 0.f, a2 = 0.f, a3 = 0.f, a4 = 0.f;
    for (int j = js; j < je; j++) {
        const unsigned s = sorted[j] >> PB_SHIFT;
        const float4 xr4 = *(const float4*)(x8 + (size_t)s * 8);
        const float xr5 = x8[(size_t)s * 8 + 4];
        a0 += xr4.x; a1 += xr4.y; a2 += xr4.z; a3 += xr4.w; a4 += xr5;
    }
    if (half) {
        float* st = stage + node * 6;
        st[0] = a0; st[1] = a1; st[2] = a2; st[3] = a3; st[4] = a4;
    }
    __syncthreads();
    if (!half && node < nloc) {
        const float* st = stage + node * 6;
        float* o = part + (size_t)sub * ((size_t)N * 6) + (size_t)(lo + node) * 6;
        o[0] = a0 + st[0];
        o[1] = a1 + st[1];
        o[2] = a2 + st[2];
        o[3] = a3 + st[3];
        o[4] = a4 + st[4];
        o[5] = (float)len;
    }
}

// ---------------------------------------------------------------------------
// Fallback binned-rescan edge kernel.
__global__ __launch_bounds__(1024) void k_edge_bin(const unsigned int* __restrict__ ei,
                                                   const float* __restrict__ x,
                                                   const int* __restrict__ flag,
                                                   float* __restrict__ part,
                                                   int E, int nchunk, int N) {
    __shared__ float acc[BINSZ * 6];
    const int bin = blockIdx.x % NBINS;
    const int chunk = blockIdx.x / NBINS;
    const int lo = bin * BINSZ;
    const int hi = (lo + BINSZ < N) ? (lo + BINSZ) : N;
    const int nloc = hi - lo;
    for (int i = threadIdx.x; i < nloc * 6; i += 1024) acc[i] = 0.0f;
    __syncthreads();

    const int is64 = *flag;
    const long long ce = ((long long)E + nchunk - 1) / nchunk;
    const long long e0 = (long long)chunk * ce;
    long long e1 = e0 + ce;
    if (e1 > E) e1 = E;

    for (long long e = e0 + threadIdx.x; e < e1; e += 1024) {
        const int d = is64 ? (int)ei[2 * ((size_t)E + (size_t)e)] : (int)ei[(size_t)E + (size_t)e];
        if (d >= lo && d < hi) {
            const int s = is64 ? (int)ei[2 * (size_t)e] : (int)ei[(size_t)e];
            const float* xr = x + (size_t)s * INC;
            float* a = acc + (d - lo) * 6;
            atomicAdd(a + 0, xr[0]);
            atomicAdd(a + 1, xr[1]);
            atomicAdd(a + 2, xr[2]);
            atomicAdd(a + 3, xr[3]);
            atomicAdd(a + 4, xr[4]);
            atomicAdd(a + 5, 1.0f);
        }
    }
    __syncthreads();
    float* o = part + (size_t)chunk * ((size_t)N * 6) + (size_t)lo * 6;
    for (int i = threadIdx.x; i < nloc * 6; i += 1024) o[i] = acc[i];
}

// ---------------------------------------------------------------------------
// Reduce partials + node update.
__global__ void k_node2(const float* __restrict__ x, const float* __restrict__ part,
                        const float* __restrict__ W1, const float* __restrict__ root1,
                        const float* __restrict__ b1, float* __restrict__ h,
                        int N, int nchunk) {
    int n = blockIdx.x * blockDim.x + threadIdx.x;
    if (n >= N) return;
    float s[6] = {0.f, 0.f, 0.f, 0.f, 0.f, 0.f};
    for (int c = 0; c < nchunk; c++) {
        const float* p = part + (size_t)c * ((size_t)N * 6) + (size_t)n * 6;
#pragma unroll
        for (int j = 0; j < 6; j++) s[j] += p[j];
    }
    const float inv = 1.0f / fmaxf(s[5], 1.0f);
    float xs[INC], xv[INC];
#pragma unroll
    for (int c = 0; c < INC; c++) {
        xs[c] = s[c] * inv;
        xv[c] = x[(size_t)n * INC + c];
    }
    float hv[H1C];
#pragma unroll
    for (int j = 0; j < H1C; j++) {
        float v = b1[j];
#pragma unroll
        for (int c = 0; c < INC; c++)
            v = fmaf(xs[c], W1[c * H1C + j], fmaf(xv[c], root1[c * H1C + j], v));
        hv[j] = fmaxf(v, 0.0f);  // relu(leaky(relu(v))) == relu(v)
    }
    float4* hp = (float4*)(h + (size_t)n * H1C);
#pragma unroll
    for (int q = 0; q < 4; q++)
        hp[q] = make_float4(hv[4 * q], hv[4 * q + 1], hv[4 * q + 2], hv[4 * q + 3]);
}

// ---------------------------------------------------------------------------
// Pooling GEMM: lane owns a float2 of pos columns; acc = 2x16 = 32 VGPR.
__global__ __launch_bounds__(512, 2) void k_pool(const float* __restrict__ pos,
                                                 const float* __restrict__ h,
                                                 float* __restrict__ xp_part, int N, int nb) {
    __shared__ float red[KCL * 17];
    const int tid = threadIdx.x;
    const int c2 = tid & 127;        // col pair
    const int w = tid >> 7;          // node sub-stream (0..3)
    const int chunk = (N + nb - 1) / nb;
    const int n0 = blockIdx.x * chunk;
    const int n1 = min(n0 + chunk, N);

    float acc0[H1C], acc1[H1C];
#pragma unroll
    for (int j = 0; j < H1C; j++) { acc0[j] = 0.0f; acc1[j] = 0.0f; }

    const float2* pos2 = (const float2*)pos;   // row stride = 128 float2

#pragma unroll 4
    for (int n = n0 + w; n < n1; n += 4) {
        const float2 p = pos2[(size_t)n * 128 + c2];
        const float4* hr = (const float4*)(h + (size_t)n * H1C);
        const float4 h0 = hr[0], h1 = hr[1], h2 = hr[2], h3 = hr[3];
        const float hv[H1C] = {h0.x, h0.y, h0.z, h0.w, h1.x, h1.y, h1.z, h1.w,
                               h2.x, h2.y, h2.z, h2.w, h3.x, h3.y, h3.z, h3.w};
#pragma unroll
        for (int j = 0; j < H1C; j++) {
            acc0[j] = fmaf(p.x, hv[j], acc0[j]);
            acc1[j] = fmaf(p.y, hv[j], acc1[j]);
        }
    }

    for (int i = tid; i < KCL * 17; i += 512) red[i] = 0.0f;
    __syncthreads();
#pragma unroll
    for (int j = 0; j < H1C; j++) {
        atomicAdd(&red[(2 * c2 + 0) * 17 + j], acc0[j]);   // 4-way contention max
        atomicAdd(&red[(2 * c2 + 1) * 17 + j], acc1[j]);
    }
    __syncthreads();
    float* o = xp_part + (size_t)blockIdx.x * (KCL * H1C);
    for (int i = tid; i < KCL * H1C; i += 512) o[i] = red[(i >> 4) * 17 + (i & 15)];
}

// ---------------------------------------------------------------------------
__global__ __launch_bounds__(1024) void k_xpred(const float* __restrict__ xp_part,
                                                float* __restrict__ xp, int nb) {
    __shared__ float r[1024];
    const int li = threadIdx.x & 63;
    const int sub = threadIdx.x >> 6;      // 0..15
    const int i = blockIdx.x * 64 + li;
    float s = 0.0f;
    for (int b = sub; b < nb; b += 16) s += xp_part[(size_t)b * (KCL * H1C) + i];
    r[threadIdx.x] = s;
    __syncthreads();
    if (threadIdx.x < 512) r[threadIdx.x] += r[threadIdx.x + 512];
    __syncthreads();
    if (threadIdx.x < 256) r[threadIdx.x] += r[threadIdx.x + 256];
    __syncthreads();
    if (threadIdx.x < 128) r[threadIdx.x] += r[threadIdx.x + 128];
    __syncthreads();
    if (threadIdx.x < 64) xp[i] = r[threadIdx.x] + r[threadIdx.x + 64];
}

// ---------------------------------------------------------------------------
// Tail: adj strictly positive => mask all-ones, deg2 = 256.
__global__ __launch_bounds__(256) void k_tail(const float* __restrict__ xp,
                                              const float* __restrict__ W2,
                                              const float* __restrict__ root2,
                                              const float* __restrict__ b2,
                                              const float* __restrict__ lw1,
                                              const float* __restrict__ lb1,
                                              const float* __restrict__ lw2,
                                              const float* __restrict__ lb2,
                                              float* __restrict__ out) {
    __shared__ float red[4][H2C];
    __shared__ float bcast[H2C];
    const int t = threadIdx.x;
    const int wv = t >> 6;
    const int lane = t & 63;

    float row[H1C];
#pragma unroll
    for (int c = 0; c < H1C; c++) row[c] = xp[t * H1C + c];

    float v1[H2C];
#pragma unroll
    for (int j = 0; j < H2C; j++) {
        float v = 0.0f;
#pragma unroll
        for (int c = 0; c < H1C; c++) v = fmaf(row[c], W2[c * H2C + j], v);
        v1[j] = v;
    }
#pragma unroll
    for (int off = 1; off < 64; off <<= 1) {
#pragma unroll
        for (int j = 0; j < H2C; j++) v1[j] += __shfl_xor(v1[j], off);
    }
    if (lane == 0) {
#pragma unroll
        for (int j = 0; j < H2C; j++) red[wv][j] = v1[j];
    }
    __syncthreads();
    if (t < H2C) bcast[t] = red[0][t] + red[1][t] + red[2][t] + red[3][t];
    __syncthreads();

    float v2[H2C];
#pragma unroll
    for (int j = 0; j < H2C; j++) {
        float v = bcast[j] * (1.0f / KCL) + b2[j];
#pragma unroll
        for (int c = 0; c < H1C; c++) v = fmaf(row[c], root2[c * H2C + j], v);
        v2[j] = fmaxf(v, 0.0f);
    }
#pragma unroll
    for (int off = 1; off < 64; off <<= 1) {
#pragma unroll
        for (int j = 0; j < H2C; j++) v2[j] += __shfl_xor(v2[j], off);
    }
    if (lane == 0) {
#pragma unroll
        for (int j = 0; j < H2C; j++) red[wv][j] = v2[j];
    }
    __syncthreads();

    if (t == 0) {
        float g[H2C];
#pragma unroll
        for (int j = 0; j < H2C; j++)
            g[j] = (red[0][j] + red[1][j] + red[2][j] + red[3][j]) * (1.0f / KCL);
        float u[8];
#pragma unroll
        for (int a = 0; a < 8; a++) {
            float v = lb1[a];
#pragma unroll
            for (int j = 0; j < H2C; j++) v = fmaf(g[j], lw1[j * 8 + a], v);
            u[a] = v > 0.0f ? v : 0.1f * v;
        }
#pragma unroll
        for (int o = 0; o < 2; o++) {
            float v = lb2[o];
#pragma unroll
            for (int a = 0; a < 8; a++) v = fmaf(u[a], lw2[a * 2 + o], v);
            out[o] = v;
        }
    }
}

// ---------------------------------------------------------------------------
extern "C" void kernel_launch(void* const* d_in, const int* in_sizes, int n_in,
                              void* d_out, int out_size, void* d_ws, size_t ws_size,
                              hipStream_t stream) {
    const float* x         = (const float*)d_in[0];
    const unsigned int* ei = (const unsigned int*)d_in[1];
    // d_in[2] = edge_attr: unused (adj has no exact zeros -> mask all-ones)
    const float* pos   = (const float*)d_in[3];
    const float* W1    = (const float*)d_in[4];
    const float* root1 = (const float*)d_in[5];
    const float* b1    = (const float*)d_in[6];
    const float* W2    = (const float*)d_in[7];
    const float* root2 = (const float*)d_in[8];
    const float* b2    = (const float*)d_in[9];
    const float* lw1   = (const float*)d_in[10];
    const float* lb1   = (const float*)d_in[11];
    const float* lw2   = (const float*)d_in[12];
    const float* lb2   = (const float*)d_in[13];
    float* out = (float*)d_out;

    const int N = in_sizes[0] / INC;  // 100000
    const int E = in_sizes[1] / 2;    // 3200000
    const int NB = (N + PB_SZ - 1) >> PB_SHIFT;

    // workspace prefix (floats): [xp 4096][flag 16][h N*16][REGION ...]
    float* ws    = (float*)d_ws;
    float* xp    = ws;
    int*   flag  = (int*)(xp + KCL * H1C);
    float* h     = (float*)(flag + 16);
    float* regio = h + (size_t)N * H1C;

    const size_t pref_floats = (size_t)(KCL * H1C) + 16 + (size_t)N * H1C;
    const size_t region_floats = ws_size / 4 > pref_floats ? ws_size / 4 - pref_floats : 0;
    // fast path region: part[PB_S*N*6] | x8[N*8] | bucket[NB*PB_C] | gcur[256]
    const size_t fast_floats = (size_t)PB_S * N * 6 + (size_t)N * 8 + (size_t)NB * PB_C + 256;

    if (region_floats >= fast_floats && N <= 131072 && NB <= PB_NBMAX) {
        float* part      = regio;
        float* x8        = part + (size_t)PB_S * N * 6;
        unsigned* bucket = (unsigned*)(x8 + (size_t)N * 8);
        unsigned* gcur   = bucket + (size_t)NB * PB_C;
        const int P = (E + PB_M - 1) / PB_M;

        k_setup<<<(N + 255) / 256, 256, 0, stream>>>(x, x8, ei, flag, gcur, N, NB);
        k_part<<<P, 1024, 0, stream>>>(ei, flag, gcur, bucket, E, NB);
        k_gather<<<NB * PB_S, 1024, 0, stream>>>(bucket, gcur, x8, part, N, NB);
        k_node2<<<(N + 255) / 256, 256, 0, stream>>>(x, part, W1, root1, b1, h, N, PB_S);

        // xp_part reuses x8/bucket space (dead after k_gather):
        // 512 slabs * 4096 floats = 2.1M < N*8 + NB*PB_C
        float* xp_part = x8;
        k_pool<<<POOL_NB, 512, 0, stream>>>(pos, h, xp_part, N, POOL_NB);
        k_xpred<<<64, 1024, 0, stream>>>(xp_part, xp, POOL_NB);
    } else {
        // fallback: binned rescan with as many chunks as fit (reserve pool slabs)
        size_t avail = region_floats > (size_t)POOL_NB * KCL * H1C
                     ? region_floats - (size_t)POOL_NB * KCL * H1C : 0;
        int nchunk = (int)(avail / ((size_t)N * 6));
        if (nchunk > MAXCHUNK) nchunk = MAXCHUNK;
        if (nchunk < 1) nchunk = 1;
        float* part = regio;
        float* xp_part = part + (size_t)nchunk * N * 6;
        k_detect<<<1, 64, 0, stream>>>(ei, flag);
        k_edge_bin<<<NBINS * nchunk, 1024, 0, stream>>>(ei, x, flag, part, E, nchunk, N);
        k_node2<<<(N + 255) / 256, 256, 0, stream>>>(x, part, W1, root1, b1, h, N, nchunk);
        k_pool<<<POOL_NB, 512, 0, stream>>>(pos, h, xp_part, N, POOL_NB);
        k_xpred<<<64, 1024, 0, stream>>>(xp_part, xp, POOL_NB);
    }
    k_tail<<<1, 256, 0, stream>>>(xp, W2, root2, b2, lw1, lb1, lw2, lb2, out);
}

// Round 8
// 117.954 us; speedup vs baseline: 3.0205x; 1.4114x over previous
//
#include <hip/hip_runtime.h>

#define INC 5
#define H1C 16
#define H2C 32
#define KCL 256

// fallback (rescan) params
#define NBINS 40
#define BINSZ 2500
#define MAXCHUNK 12

// partition params
#define PB_SHIFT 9
#define PB_SZ 512               // nodes per bin
#define PB_NBMAX 256
#define PB_C 18432              // bucket capacity per bin (mean 16384 + 16 sigma)
#define PB_M 6144               // edges per partition block
#define PB_ETPB 6               // PB_M / 1024
#define PB_S 2                  // phase-2 sub-splits per bin
#define PB_GMAX 9216            // max entries per gather block = PB_C/PB_S
#define PB_GETG 9               // ceil(PB_GMAX/1024)

#define POOL_NB 512
#define PT 32                   // pool tile: nodes per LDS tile

typedef __attribute__((address_space(1))) const unsigned gls_src;
typedef __attribute__((address_space(3))) unsigned gls_dst;

// ---------------------------------------------------------------------------
// Fused setup: x8 expansion + gcur init + int64/int32 detect.
__global__ void k_setup(const float* __restrict__ x, float* __restrict__ x8,
                        const unsigned int* __restrict__ ei, int* __restrict__ flag,
                        unsigned* __restrict__ gcur, int N, int NB) {
    int n = blockIdx.x * blockDim.x + threadIdx.x;
    if (n < N) {
        const float* xr = x + (size_t)n * INC;
        float4* o = (float4*)(x8 + (size_t)n * 8);
        o[0] = make_float4(xr[0], xr[1], xr[2], xr[3]);
        o[1] = make_float4(xr[4], 0.0f, 0.0f, 0.0f);
    }
    if (blockIdx.x == 0) {
        if (threadIdx.x < (unsigned)NB) gcur[threadIdx.x] = (unsigned)threadIdx.x * PB_C;
        if (threadIdx.x == 0) {
            int is64 = 1;
            for (int i = 1; i < 32; i += 2)
                if (ei[i] != 0u) is64 = 0;
            *flag = is64;
        }
    }
}

// standalone detect for the fallback path
__global__ void k_detect(const unsigned int* __restrict__ ei, int* __restrict__ flag) {
    if (blockIdx.x == 0 && threadIdx.x == 0) {
        int is64 = 1;
        for (int i = 1; i < 32; i += 2)
            if (ei[i] != 0u) is64 = 0;
        *flag = is64;
    }
}

// ---------------------------------------------------------------------------
// Phase 1: partition edges into dst-bins (LDS histogram + counting sort +
// coalesced bucket writes of packed entries src<<9 | dst&511).
__global__ __launch_bounds__(1024) void k_part(const unsigned int* __restrict__ ei,
                                               const int* __restrict__ flag,
                                               unsigned* __restrict__ gcur,
                                               unsigned* __restrict__ bucket,
                                               int E, int NB) {
    __shared__ int hist[PB_NBMAX];
    __shared__ int lbase[PB_NBMAX];
    __shared__ unsigned gbase[PB_NBMAX];
    __shared__ int sc[PB_NBMAX];
    __shared__ unsigned sorted[PB_M];
    __shared__ unsigned char sbin[PB_M];

    const int tid = threadIdx.x;
    const int e0 = blockIdx.x * PB_M;
    int m = E - e0; if (m > PB_M) m = PB_M;

    for (int i = tid; i < PB_NBMAX; i += 1024) hist[i] = 0;
    __syncthreads();

    const int is64 = *flag;  // uniform
    unsigned ee[PB_ETPB]; int eb[PB_ETPB]; int er[PB_ETPB];

#pragma unroll
    for (int ii = 0; ii < PB_ETPB; ii++) {
        const int off = tid + ii * 1024;
        eb[ii] = -1; ee[ii] = 0u; er[ii] = 0;
        if (off < m) {
            const int e = e0 + off;
            unsigned d, s;
            if (is64) { d = ei[2 * ((size_t)E + (size_t)e)]; s = ei[2 * (size_t)e]; }
            else      { d = ei[(size_t)E + (size_t)e];       s = ei[(size_t)e]; }
            const int b = (int)(d >> PB_SHIFT);
            eb[ii] = b;
            ee[ii] = (s << PB_SHIFT) | (d & (PB_SZ - 1));
            er[ii] = atomicAdd(&hist[b], 1);
        }
    }
    __syncthreads();

    // inclusive scan of hist (256 entries, Hillis-Steele)
    if (tid < PB_NBMAX) sc[tid] = hist[tid];
    __syncthreads();
    for (int st = 1; st < PB_NBMAX; st <<= 1) {
        int v = 0;
        if (tid < PB_NBMAX && tid >= st) v = sc[tid - st];
        __syncthreads();
        if (tid < PB_NBMAX) sc[tid] += v;
        __syncthreads();
    }
    if (tid < PB_NBMAX) lbase[tid] = sc[tid] - hist[tid];
    if (tid < NB) gbase[tid] = atomicAdd(&gcur[tid], (unsigned)hist[tid]);
    __syncthreads();

#pragma unroll
    for (int ii = 0; ii < PB_ETPB; ii++) {
        if (eb[ii] >= 0) {
            const int j = lbase[eb[ii]] + er[ii];
            sorted[j] = ee[ii];
            sbin[j] = (unsigned char)eb[ii];
        }
    }
    __syncthreads();

    for (int j = tid; j < m; j += 1024) {
        const int b = (int)sbin[j];
        const unsigned g = gbase[b] + (unsigned)(j - lbase[b]);
        if (g < (unsigned)(b + 1) * PB_C) bucket[g] = sorted[j];  // overflow guard
    }
}

// ---------------------------------------------------------------------------
// Phase 2 (atomic-free accumulate): counting-sort the slice by local dst in
// LDS, then 2 threads per node accumulate x8[src] in REGISTERS.
__global__ __launch_bounds__(1024) void k_gather(const unsigned* __restrict__ bucket,
                                                 const unsigned* __restrict__ gcur,
                                                 const float* __restrict__ x8,
                                                 float* __restrict__ part,
                                                 int N, int NB) {
    __shared__ unsigned sorted[PB_GMAX];   // 36 KB
    __shared__ int hist[PB_SZ];
    __shared__ int sc[PB_SZ];
    __shared__ int lbase[PB_SZ];
    __shared__ float stage[PB_SZ * 6];     // 12 KB

    const int b = blockIdx.x / PB_S;
    const int sub = blockIdx.x % PB_S;
    const int tid = threadIdx.x;
    const int lo = b << PB_SHIFT;
    int hi = lo + PB_SZ; if (hi > N) hi = N;
    const int nloc = hi - lo;

    int cnt = (int)(gcur[b] - (unsigned)b * PB_C);
    if (cnt > PB_C) cnt = PB_C;
    const int i0 = (cnt * sub) / PB_S;
    const int i1 = (cnt * (sub + 1)) / PB_S;
    const int m = i1 - i0;
    const unsigned* bk = bucket + (size_t)b * PB_C + i0;

    for (int i = tid; i < PB_SZ; i += 1024) hist[i] = 0;
    __syncthreads();

    unsigned ee[PB_GETG]; int edl[PB_GETG]; int er[PB_GETG];
#pragma unroll
    for (int ii = 0; ii < PB_GETG; ii++) {
        const int off = tid + ii * 1024;
        edl[ii] = -1; ee[ii] = 0u; er[ii] = 0;
        if (off < m) {
            const unsigned e = bk[off];
            const int dl = (int)(e & (PB_SZ - 1));
            edl[ii] = dl;
            ee[ii] = e;
            er[ii] = atomicAdd(&hist[dl], 1);
        }
    }
    __syncthreads();

    // exclusive scan of 512-entry hist
    if (tid < PB_SZ) sc[tid] = hist[tid];
    __syncthreads();
    for (int st = 1; st < PB_SZ; st <<= 1) {
        int v = 0;
        if (tid < PB_SZ && tid >= st) v = sc[tid - st];
        __syncthreads();
        if (tid < PB_SZ) sc[tid] += v;
        __syncthreads();
    }
    if (tid < PB_SZ) lbase[tid] = sc[tid] - hist[tid];
    __syncthreads();

#pragma unroll
    for (int ii = 0; ii < PB_GETG; ii++)
        if (edl[ii] >= 0) sorted[lbase[edl[ii]] + er[ii]] = ee[ii];
    __syncthreads();

    // register accumulation: 2 threads per node, half a run each
    const int node = tid & (PB_SZ - 1);
    const int half = tid >> PB_SHIFT;      // 0 or 1
    const int start = lbase[node];
    const int len = hist[node];
    const int js = start + (half ? (len >> 1) : 0);
    const int je = start + (half ? len : (len >> 1));
    float a0 = 0.f, a1 = 0.f, a2 = 0.f, a3 = 0.f, a4 = 0.f;
    for (int j = js; j < je; j++) {
        const unsigned s = sorted[j] >> PB_SHIFT;
        const float4 xr4 = *(const float4*)(x8 + (size_t)s * 8);
        const float xr5 = x8[(size_t)s * 8 + 4];
        a0 += xr4.x; a1 += xr4.y; a2 += xr4.z; a3 += xr4.w; a4 += xr5;
    }
    if (half) {
        float* st = stage + node * 6;
        st[0] = a0; st[1] = a1; st[2] = a2; st[3] = a3; st[4] = a4;
    }
    __syncthreads();
    if (!half && node < nloc) {
        const float* st = stage + node * 6;
        float* o = part + (size_t)sub * ((size_t)N * 6) + (size_t)(lo + node) * 6;
        o[0] = a0 + st[0];
        o[1] = a1 + st[1];
        o[2] = a2 + st[2];
        o[3] = a3 + st[3];
        o[4] = a4 + st[4];
        o[5] = (float)len;
    }
}

// ---------------------------------------------------------------------------
// Fallback binned-rescan edge kernel.
__global__ __launch_bounds__(1024) void k_edge_bin(const unsigned int* __restrict__ ei,
                                                   const float* __restrict__ x,
                                                   const int* __restrict__ flag,
                                                   float* __restrict__ part,
                                                   int E, int nchunk, int N) {
    __shared__ float acc[BINSZ * 6];
    const int bin = blockIdx.x % NBINS;
    const int chunk = blockIdx.x / NBINS;
    const int lo = bin * BINSZ;
    const int hi = (lo + BINSZ < N) ? (lo + BINSZ) : N;
    const int nloc = hi - lo;
    for (int i = threadIdx.x; i < nloc * 6; i += 1024) acc[i] = 0.0f;
    __syncthreads();

    const int is64 = *flag;
    const long long ce = ((long long)E + nchunk - 1) / nchunk;
    const long long e0 = (long long)chunk * ce;
    long long e1 = e0 + ce;
    if (e1 > E) e1 = E;

    for (long long e = e0 + threadIdx.x; e < e1; e += 1024) {
        const int d = is64 ? (int)ei[2 * ((size_t)E + (size_t)e)] : (int)ei[(size_t)E + (size_t)e];
        if (d >= lo && d < hi) {
            const int s = is64 ? (int)ei[2 * (size_t)e] : (int)ei[(size_t)e];
            const float* xr = x + (size_t)s * INC;
            float* a = acc + (d - lo) * 6;
            atomicAdd(a + 0, xr[0]);
            atomicAdd(a + 1, xr[1]);
            atomicAdd(a + 2, xr[2]);
            atomicAdd(a + 3, xr[3]);
            atomicAdd(a + 4, xr[4]);
            atomicAdd(a + 5, 1.0f);
        }
    }
    __syncthreads();
    float* o = part + (size_t)chunk * ((size_t)N * 6) + (size_t)lo * 6;
    for (int i = threadIdx.x; i < nloc * 6; i += 1024) o[i] = acc[i];
}

// ---------------------------------------------------------------------------
// Reduce partials + node update.
__global__ void k_node2(const float* __restrict__ x, const float* __restrict__ part,
                        const float* __restrict__ W1, const float* __restrict__ root1,
                        const float* __restrict__ b1, float* __restrict__ h,
                        int N, int nchunk) {
    int n = blockIdx.x * blockDim.x + threadIdx.x;
    if (n >= N) return;
    float s[6] = {0.f, 0.f, 0.f, 0.f, 0.f, 0.f};
    for (int c = 0; c < nchunk; c++) {
        const float* p = part + (size_t)c * ((size_t)N * 6) + (size_t)n * 6;
#pragma unroll
        for (int j = 0; j < 6; j++) s[j] += p[j];
    }
    const float inv = 1.0f / fmaxf(s[5], 1.0f);
    float xs[INC], xv[INC];
#pragma unroll
    for (int c = 0; c < INC; c++) {
        xs[c] = s[c] * inv;
        xv[c] = x[(size_t)n * INC + c];
    }
    float hv[H1C];
#pragma unroll
    for (int j = 0; j < H1C; j++) {
        float v = b1[j];
#pragma unroll
        for (int c = 0; c < INC; c++)
            v = fmaf(xs[c], W1[c * H1C + j], fmaf(xv[c], root1[c * H1C + j], v));
        hv[j] = fmaxf(v, 0.0f);  // relu(leaky(relu(v))) == relu(v)
    }
    float4* hp = (float4*)(h + (size_t)n * H1C);
#pragma unroll
    for (int q = 0; q < 4; q++)
        hp[q] = make_float4(hv[4 * q], hv[4 * q + 1], hv[4 * q + 2], hv[4 * q + 3]);
}

// ---------------------------------------------------------------------------
// Pooling GEMM, LDS-staged via global_load_lds (zero VGPR staging):
// per tile of 32 nodes: pos tile 32KB + h tile 2KB double-buffered (68KB LDS,
// 2 blocks/CU). Thread owns (k=tid&255, j-half=tid>>8): acc[8] registers.
// __syncthreads() at loop end = vmcnt(0) drain for the NEXT tile's loads,
// which were issued BEFORE compute -> HBM latency hides under compute.
__global__ __launch_bounds__(512) void k_pool(const float* __restrict__ pos,
                                              const float* __restrict__ h,
                                              float* __restrict__ xp_part, int N, int nb) {
    __shared__ float pbuf[2][PT * KCL];    // 2 x 32 KB
    __shared__ float hbuf[2][PT * H1C];    // 2 x 2 KB
    const int tid = threadIdx.x;
    const int k = tid & 255;
    const int jh = tid >> 8;               // 0/1
    const int wid = tid >> 6;              // wave 0..7
    const int lane = tid & 63;
    const int chunk = (N + nb - 1) / nb;
    const int n0 = blockIdx.x * chunk;
    const int n1 = min(n0 + chunk, N);
    const int ntile = (n1 > n0) ? (n1 - n0 + PT - 1) / PT : 0;

    const size_t maxp = (size_t)N * KCL - 4;
    const size_t maxh = (size_t)N * H1C - 4;

    float acc[8];
#pragma unroll
    for (int j = 0; j < 8; j++) acc[j] = 0.0f;

    // stage tile 'tile' into buffer bf: LDS layout mirrors global linearly.
    // LDS dst is wave-uniform (HW adds lane*16); global src is per-lane,
    // clamped in-bounds (tail garbage is never read by compute).
    auto STAGE = [&](int bf, int tile) {
        const size_t nt0 = (size_t)n0 + (size_t)tile * PT;
        const size_t pb = nt0 * KCL;
#pragma unroll
        for (int c = 0; c < 4; ++c) {
            const int off = (wid * 4 + c) * 256;
            size_t fi = pb + (size_t)off + (size_t)lane * 4;
            if (fi > maxp) fi = maxp;
            __builtin_amdgcn_global_load_lds((gls_src*)(pos + fi),
                                             (gls_dst*)&pbuf[bf][off], 16, 0, 0);
        }
        if (wid < 2) {
            const int off = wid * 256;
            size_t fi = nt0 * H1C + (size_t)off + (size_t)lane * 4;
            if (fi > maxh) fi = maxh;
            __builtin_amdgcn_global_load_lds((gls_src*)(h + fi),
                                             (gls_dst*)&hbuf[bf][off], 16, 0, 0);
        }
    };

    int buf = 0;
    if (ntile > 0) {
        STAGE(0, 0);
        __syncthreads();   // implicit vmcnt(0): tile 0 resident
    }
    for (int t = 0; t < ntile; ++t) {
        if (t + 1 < ntile) STAGE(buf ^ 1, t + 1);   // issue next-tile loads FIRST
        const int nt0 = n0 + t * PT;
        const int tcnt = min(PT, n1 - nt0);
        for (int tt = 0; tt < tcnt; ++tt) {
            const float p = pbuf[buf][tt * KCL + k];
            const float4* hr = (const float4*)&hbuf[buf][tt * H1C + jh * 8];
            const float4 ha = hr[0], hb = hr[1];
            acc[0] = fmaf(p, ha.x, acc[0]); acc[1] = fmaf(p, ha.y, acc[1]);
            acc[2] = fmaf(p, ha.z, acc[2]); acc[3] = fmaf(p, ha.w, acc[3]);
            acc[4] = fmaf(p, hb.x, acc[4]); acc[5] = fmaf(p, hb.y, acc[5]);
            acc[6] = fmaf(p, hb.z, acc[6]); acc[7] = fmaf(p, hb.w, acc[7]);
        }
        __syncthreads();   // vmcnt(0) drain of next tile + buffer handoff
        buf ^= 1;
    }

    float* o = xp_part + (size_t)blockIdx.x * (KCL * H1C) + k * H1C + jh * 8;
    *(float4*)o = make_float4(acc[0], acc[1], acc[2], acc[3]);
    *(float4*)(o + 4) = make_float4(acc[4], acc[5], acc[6], acc[7]);
}

// ---------------------------------------------------------------------------
__global__ __launch_bounds__(1024) void k_xpred(const float* __restrict__ xp_part,
                                                float* __restrict__ xp, int nb) {
    __shared__ float r[1024];
    const int li = threadIdx.x & 63;
    const int sub = threadIdx.x >> 6;      // 0..15
    const int i = blockIdx.x * 64 + li;
    float s = 0.0f;
    for (int b = sub; b < nb; b += 16) s += xp_part[(size_t)b * (KCL * H1C) + i];
    r[threadIdx.x] = s;
    __syncthreads();
    if (threadIdx.x < 512) r[threadIdx.x] += r[threadIdx.x + 512];
    __syncthreads();
    if (threadIdx.x < 256) r[threadIdx.x] += r[threadIdx.x + 256];
    __syncthreads();
    if (threadIdx.x < 128) r[threadIdx.x] += r[threadIdx.x + 128];
    __syncthreads();
    if (threadIdx.x < 64) xp[i] = r[threadIdx.x] + r[threadIdx.x + 64];
}

// ---------------------------------------------------------------------------
// Tail: adj strictly positive => mask all-ones, deg2 = 256.
__global__ __launch_bounds__(256) void k_tail(const float* __restrict__ xp,
                                              const float* __restrict__ W2,
                                              const float* __restrict__ root2,
                                              const float* __restrict__ b2,
                                              const float* __restrict__ lw1,
                                              const float* __restrict__ lb1,
                                              const float* __restrict__ lw2,
                                              const float* __restrict__ lb2,
                                              float* __restrict__ out) {
    __shared__ float red[4][H2C];
    __shared__ float bcast[H2C];
    const int t = threadIdx.x;
    const int wv = t >> 6;
    const int lane = t & 63;

    float row[H1C];
#pragma unroll
    for (int c = 0; c < H1C; c++) row[c] = xp[t * H1C + c];

    float v1[H2C];
#pragma unroll
    for (int j = 0; j < H2C; j++) {
        float v = 0.0f;
#pragma unroll
        for (int c = 0; c < H1C; c++) v = fmaf(row[c], W2[c * H2C + j], v);
        v1[j] = v;
    }
#pragma unroll
    for (int off = 1; off < 64; off <<= 1) {
#pragma unroll
        for (int j = 0; j < H2C; j++) v1[j] += __shfl_xor(v1[j], off);
    }
    if (lane == 0) {
#pragma unroll
        for (int j = 0; j < H2C; j++) red[wv][j] = v1[j];
    }
    __syncthreads();
    if (t < H2C) bcast[t] = red[0][t] + red[1][t] + red[2][t] + red[3][t];
    __syncthreads();

    float v2[H2C];
#pragma unroll
    for (int j = 0; j < H2C; j++) {
        float v = bcast[j] * (1.0f / KCL) + b2[j];
#pragma unroll
        for (int c = 0; c < H1C; c++) v = fmaf(row[c], root2[c * H2C + j], v);
        v2[j] = fmaxf(v, 0.0f);
    }
#pragma unroll
    for (int off = 1; off < 64; off <<= 1) {
#pragma unroll
        for (int j = 0; j < H2C; j++) v2[j] += __shfl_xor(v2[j], off);
    }
    if (lane == 0) {
#pragma unroll
        for (int j = 0; j < H2C; j++) red[wv][j] = v2[j];
    }
    __syncthreads();

    if (t == 0) {
        float g[H2C];
#pragma unroll
        for (int j = 0; j < H2C; j++)
            g[j] = (red[0][j] + red[1][j] + red[2][j] + red[3][j]) * (1.0f / KCL);
        float u[8];
#pragma unroll
        for (int a = 0; a < 8; a++) {
            float v = lb1[a];
#pragma unroll
            for (int j = 0; j < H2C; j++) v = fmaf(g[j], lw1[j * 8 + a], v);
            u[a] = v > 0.0f ? v : 0.1f * v;
        }
#pragma unroll
        for (int o = 0; o < 2; o++) {
            float v = lb2[o];
#pragma unroll
            for (int a = 0; a < 8; a++) v = fmaf(u[a], lw2[a * 2 + o], v);
            out[o] = v;
        }
    }
}

// ---------------------------------------------------------------------------
extern "C" void kernel_launch(void* const* d_in, const int* in_sizes, int n_in,
                              void* d_out, int out_size, void* d_ws, size_t ws_size,
                              hipStream_t stream) {
    const float* x         = (const float*)d_in[0];
    const unsigned int* ei = (const unsigned int*)d_in[1];
    // d_in[2] = edge_attr: unused (adj has no exact zeros -> mask all-ones)
    const float* pos   = (const float*)d_in[3];
    const float* W1    = (const float*)d_in[4];
    const float* root1 = (const float*)d_in[5];
    const float* b1    = (const float*)d_in[6];
    const float* W2    = (const float*)d_in[7];
    const float* root2 = (const float*)d_in[8];
    const float* b2    = (const float*)d_in[9];
    const float* lw1   = (const float*)d_in[10];
    const float* lb1   = (const float*)d_in[11];
    const float* lw2   = (const float*)d_in[12];
    const float* lb2   = (const float*)d_in[13];
    float* out = (float*)d_out;

    const int N = in_sizes[0] / INC;  // 100000
    const int E = in_sizes[1] / 2;    // 3200000
    const int NB = (N + PB_SZ - 1) >> PB_SHIFT;

    // workspace prefix (floats): [xp 4096][flag 16][h N*16][REGION ...]
    float* ws    = (float*)d_ws;
    float* xp    = ws;
    int*   flag  = (int*)(xp + KCL * H1C);
    float* h     = (float*)(flag + 16);
    float* regio = h + (size_t)N * H1C;

    const size_t pref_floats = (size_t)(KCL * H1C) + 16 + (size_t)N * H1C;
    const size_t region_floats = ws_size / 4 > pref_floats ? ws_size / 4 - pref_floats : 0;
    // fast path region: part[PB_S*N*6] | x8[N*8] | bucket[NB*PB_C] | gcur[256]
    const size_t fast_floats = (size_t)PB_S * N * 6 + (size_t)N * 8 + (size_t)NB * PB_C + 256;

    if (region_floats >= fast_floats && N <= 131072 && NB <= PB_NBMAX) {
        float* part      = regio;
        float* x8        = part + (size_t)PB_S * N * 6;
        unsigned* bucket = (unsigned*)(x8 + (size_t)N * 8);
        unsigned* gcur   = bucket + (size_t)NB * PB_C;
        const int P = (E + PB_M - 1) / PB_M;

        k_setup<<<(N + 255) / 256, 256, 0, stream>>>(x, x8, ei, flag, gcur, N, NB);
        k_part<<<P, 1024, 0, stream>>>(ei, flag, gcur, bucket, E, NB);
        k_gather<<<NB * PB_S, 1024, 0, stream>>>(bucket, gcur, x8, part, N, NB);
        k_node2<<<(N + 255) / 256, 256, 0, stream>>>(x, part, W1, root1, b1, h, N, PB_S);

        // xp_part reuses x8/bucket space (dead after k_gather)
        float* xp_part = x8;
        k_pool<<<POOL_NB, 512, 0, stream>>>(pos, h, xp_part, N, POOL_NB);
        k_xpred<<<64, 1024, 0, stream>>>(xp_part, xp, POOL_NB);
    } else {
        // fallback: binned rescan with as many chunks as fit (reserve pool slabs)
        size_t avail = region_floats > (size_t)POOL_NB * KCL * H1C
                     ? region_floats - (size_t)POOL_NB * KCL * H1C : 0;
        int nchunk = (int)(avail / ((size_t)N * 6));
        if (nchunk > MAXCHUNK) nchunk = MAXCHUNK;
        if (nchunk < 1) nchunk = 1;
        float* part = regio;
        float* xp_part = part + (size_t)nchunk * N * 6;
        k_detect<<<1, 64, 0, stream>>>(ei, flag);
        k_edge_bin<<<NBINS * nchunk, 1024, 0, stream>>>(ei, x, flag, part, E, nchunk, N);
        k_node2<<<(N + 255) / 256, 256, 0, stream>>>(x, part, W1, root1, b1, h, N, nchunk);
        k_pool<<<POOL_NB, 512, 0, stream>>>(pos, h, xp_part, N, POOL_NB);
        k_xpred<<<64, 1024, 0, stream>>>(xp_part, xp, POOL_NB);
    }
    k_tail<<<1, 256, 0, stream>>>(xp, W2, root2, b2, lw1, lb1, lw2, lb2, out);
}

// Round 9
// 110.539 us; speedup vs baseline: 3.2231x; 1.0671x over previous
//
#include <hip/hip_runtime.h>

#define INC 5
#define H1C 16
#define H2C 32
#define KCL 256

// fallback (rescan) params
#define NBINS 40
#define BINSZ 2500
#define MAXCHUNK 12

// partition params
#define PB_SHIFT 9
#define PB_SZ 512               // nodes per bin
#define PB_NBMAX 256
#define PB_C 18432              // bucket capacity per bin (mean 16384 + 16 sigma)
#define PB_M 6144               // edges per partition block
#define PB_ETPB 6               // PB_M / 1024
#define PB_S 2                  // phase-2 sub-splits per bin
#define PB_GMAX 9216            // max entries per gather block = PB_C/PB_S
#define PB_GETG 9               // ceil(PB_GMAX/1024)

#define POOL_NB 512
#define PT 32                   // pool tile: nodes per LDS tile

typedef __attribute__((address_space(1))) const unsigned gls_src;
typedef __attribute__((address_space(3))) unsigned gls_dst;

// ---------------------------------------------------------------------------
// Fused setup: x8 expansion + gcur init + int64/int32 detect.
__global__ void k_setup(const float* __restrict__ x, float* __restrict__ x8,
                        const unsigned int* __restrict__ ei, int* __restrict__ flag,
                        unsigned* __restrict__ gcur, int N, int NB) {
    int n = blockIdx.x * blockDim.x + threadIdx.x;
    if (n < N) {
        const float* xr = x + (size_t)n * INC;
        float4* o = (float4*)(x8 + (size_t)n * 8);
        o[0] = make_float4(xr[0], xr[1], xr[2], xr[3]);
        o[1] = make_float4(xr[4], 0.0f, 0.0f, 0.0f);
    }
    if (blockIdx.x == 0) {
        if (threadIdx.x < (unsigned)NB) gcur[threadIdx.x] = (unsigned)threadIdx.x * PB_C;
        if (threadIdx.x == 0) {
            int is64 = 1;
            for (int i = 1; i < 32; i += 2)
                if (ei[i] != 0u) is64 = 0;
            *flag = is64;
        }
    }
}

// standalone detect for the fallback path
__global__ void k_detect(const unsigned int* __restrict__ ei, int* __restrict__ flag) {
    if (blockIdx.x == 0 && threadIdx.x == 0) {
        int is64 = 1;
        for (int i = 1; i < 32; i += 2)
            if (ei[i] != 0u) is64 = 0;
        *flag = is64;
    }
}

// ---------------------------------------------------------------------------
// Phase 1: partition edges into dst-bins (LDS histogram + counting sort +
// coalesced bucket writes of packed entries src<<9 | dst&511).
__global__ __launch_bounds__(1024) void k_part(const unsigned int* __restrict__ ei,
                                               const int* __restrict__ flag,
                                               unsigned* __restrict__ gcur,
                                               unsigned* __restrict__ bucket,
                                               int E, int NB) {
    __shared__ int hist[PB_NBMAX];
    __shared__ int lbase[PB_NBMAX];
    __shared__ unsigned gbase[PB_NBMAX];
    __shared__ int sc[PB_NBMAX];
    __shared__ unsigned sorted[PB_M];
    __shared__ unsigned char sbin[PB_M];

    const int tid = threadIdx.x;
    const int e0 = blockIdx.x * PB_M;
    int m = E - e0; if (m > PB_M) m = PB_M;

    for (int i = tid; i < PB_NBMAX; i += 1024) hist[i] = 0;
    __syncthreads();

    const int is64 = *flag;  // uniform
    unsigned ee[PB_ETPB]; int eb[PB_ETPB]; int er[PB_ETPB];

#pragma unroll
    for (int ii = 0; ii < PB_ETPB; ii++) {
        const int off = tid + ii * 1024;
        eb[ii] = -1; ee[ii] = 0u; er[ii] = 0;
        if (off < m) {
            const int e = e0 + off;
            unsigned d, s;
            if (is64) { d = ei[2 * ((size_t)E + (size_t)e)]; s = ei[2 * (size_t)e]; }
            else      { d = ei[(size_t)E + (size_t)e];       s = ei[(size_t)e]; }
            const int b = (int)(d >> PB_SHIFT);
            eb[ii] = b;
            ee[ii] = (s << PB_SHIFT) | (d & (PB_SZ - 1));
            er[ii] = atomicAdd(&hist[b], 1);
        }
    }
    __syncthreads();

    // inclusive scan of hist (256 entries, Hillis-Steele)
    if (tid < PB_NBMAX) sc[tid] = hist[tid];
    __syncthreads();
    for (int st = 1; st < PB_NBMAX; st <<= 1) {
        int v = 0;
        if (tid < PB_NBMAX && tid >= st) v = sc[tid - st];
        __syncthreads();
        if (tid < PB_NBMAX) sc[tid] += v;
        __syncthreads();
    }
    if (tid < PB_NBMAX) lbase[tid] = sc[tid] - hist[tid];
    if (tid < NB) gbase[tid] = atomicAdd(&gcur[tid], (unsigned)hist[tid]);
    __syncthreads();

#pragma unroll
    for (int ii = 0; ii < PB_ETPB; ii++) {
        if (eb[ii] >= 0) {
            const int j = lbase[eb[ii]] + er[ii];
            sorted[j] = ee[ii];
            sbin[j] = (unsigned char)eb[ii];
        }
    }
    __syncthreads();

    for (int j = tid; j < m; j += 1024) {
        const int b = (int)sbin[j];
        const unsigned g = gbase[b] + (unsigned)(j - lbase[b]);
        if (g < (unsigned)(b + 1) * PB_C) bucket[g] = sorted[j];  // overflow guard
    }
}

// ---------------------------------------------------------------------------
// Phase 2 (atomic-free accumulate): counting-sort the slice by local dst in
// LDS, then 2 threads per node accumulate x8[src] in REGISTERS.
__global__ __launch_bounds__(1024) void k_gather(const unsigned* __restrict__ bucket,
                                                 const unsigned* __restrict__ gcur,
                                                 const float* __restrict__ x8,
                                                 float* __restrict__ part,
                                                 int N, int NB) {
    __shared__ unsigned sorted[PB_GMAX];   // 36 KB
    __shared__ int hist[PB_SZ];
    __shared__ int sc[PB_SZ];
    __shared__ int lbase[PB_SZ];
    __shared__ float stage[PB_SZ * 6];     // 12 KB

    const int b = blockIdx.x / PB_S;
    const int sub = blockIdx.x % PB_S;
    const int tid = threadIdx.x;
    const int lo = b << PB_SHIFT;
    int hi = lo + PB_SZ; if (hi > N) hi = N;
    const int nloc = hi - lo;

    int cnt = (int)(gcur[b] - (unsigned)b * PB_C);
    if (cnt > PB_C) cnt = PB_C;
    const int i0 = (cnt * sub) / PB_S;
    const int i1 = (cnt * (sub + 1)) / PB_S;
    const int m = i1 - i0;
    const unsigned* bk = bucket + (size_t)b * PB_C + i0;

    for (int i = tid; i < PB_SZ; i += 1024) hist[i] = 0;
    __syncthreads();

    unsigned ee[PB_GETG]; int edl[PB_GETG]; int er[PB_GETG];
#pragma unroll
    for (int ii = 0; ii < PB_GETG; ii++) {
        const int off = tid + ii * 1024;
        edl[ii] = -1; ee[ii] = 0u; er[ii] = 0;
        if (off < m) {
            const unsigned e = bk[off];
            const int dl = (int)(e & (PB_SZ - 1));
            edl[ii] = dl;
            ee[ii] = e;
            er[ii] = atomicAdd(&hist[dl], 1);
        }
    }
    __syncthreads();

    // exclusive scan of 512-entry hist
    if (tid < PB_SZ) sc[tid] = hist[tid];
    __syncthreads();
    for (int st = 1; st < PB_SZ; st <<= 1) {
        int v = 0;
        if (tid < PB_SZ && tid >= st) v = sc[tid - st];
        __syncthreads();
        if (tid < PB_SZ) sc[tid] += v;
        __syncthreads();
    }
    if (tid < PB_SZ) lbase[tid] = sc[tid] - hist[tid];
    __syncthreads();

#pragma unroll
    for (int ii = 0; ii < PB_GETG; ii++)
        if (edl[ii] >= 0) sorted[lbase[edl[ii]] + er[ii]] = ee[ii];
    __syncthreads();

    // register accumulation: 2 threads per node, half a run each
    const int node = tid & (PB_SZ - 1);
    const int half = tid >> PB_SHIFT;      // 0 or 1
    const int start = lbase[node];
    const int len = hist[node];
    const int js = start + (half ? (len >> 1) : 0);
    const int je = start + (half ? len : (len >> 1));
    float a0 = 0.f, a1 = 0.f, a2 = 0.f, a3 = 0.f, a4 = 0.f;
    for (int j = js; j < je; j++) {
        const unsigned s = sorted[j] >> PB_SHIFT;
        const float4 xr4 = *(const float4*)(x8 + (size_t)s * 8);
        const float xr5 = x8[(size_t)s * 8 + 4];
        a0 += xr4.x; a1 += xr4.y; a2 += xr4.z; a3 += xr4.w; a4 += xr5;
    }
    if (half) {
        float* st = stage + node * 6;
        st[0] = a0; st[1] = a1; st[2] = a2; st[3] = a3; st[4] = a4;
    }
    __syncthreads();
    if (!half && node < nloc) {
        const float* st = stage + node * 6;
        float* o = part + (size_t)sub * ((size_t)N * 6) + (size_t)(lo + node) * 6;
        o[0] = a0 + st[0];
        o[1] = a1 + st[1];
        o[2] = a2 + st[2];
        o[3] = a3 + st[3];
        o[4] = a4 + st[4];
        o[5] = (float)len;
    }
}

// ---------------------------------------------------------------------------
// Fallback binned-rescan edge kernel.
__global__ __launch_bounds__(1024) void k_edge_bin(const unsigned int* __restrict__ ei,
                                                   const float* __restrict__ x,
                                                   const int* __restrict__ flag,
                                                   float* __restrict__ part,
                                                   int E, int nchunk, int N) {
    __shared__ float acc[BINSZ * 6];
    const int bin = blockIdx.x % NBINS;
    const int chunk = blockIdx.x / NBINS;
    const int lo = bin * BINSZ;
    const int hi = (lo + BINSZ < N) ? (lo + BINSZ) : N;
    const int nloc = hi - lo;
    for (int i = threadIdx.x; i < nloc * 6; i += 1024) acc[i] = 0.0f;
    __syncthreads();

    const int is64 = *flag;
    const long long ce = ((long long)E + nchunk - 1) / nchunk;
    const long long e0 = (long long)chunk * ce;
    long long e1 = e0 + ce;
    if (e1 > E) e1 = E;

    for (long long e = e0 + threadIdx.x; e < e1; e += 1024) {
        const int d = is64 ? (int)ei[2 * ((size_t)E + (size_t)e)] : (int)ei[(size_t)E + (size_t)e];
        if (d >= lo && d < hi) {
            const int s = is64 ? (int)ei[2 * (size_t)e] : (int)ei[(size_t)e];
            const float* xr = x + (size_t)s * INC;
            float* a = acc + (d - lo) * 6;
            atomicAdd(a + 0, xr[0]);
            atomicAdd(a + 1, xr[1]);
            atomicAdd(a + 2, xr[2]);
            atomicAdd(a + 3, xr[3]);
            atomicAdd(a + 4, xr[4]);
            atomicAdd(a + 5, 1.0f);
        }
    }
    __syncthreads();
    float* o = part + (size_t)chunk * ((size_t)N * 6) + (size_t)lo * 6;
    for (int i = threadIdx.x; i < nloc * 6; i += 1024) o[i] = acc[i];
}

// ---------------------------------------------------------------------------
// Reduce partials + node update.
__global__ void k_node2(const float* __restrict__ x, const float* __restrict__ part,
                        const float* __restrict__ W1, const float* __restrict__ root1,
                        const float* __restrict__ b1, float* __restrict__ h,
                        int N, int nchunk) {
    int n = blockIdx.x * blockDim.x + threadIdx.x;
    if (n >= N) return;
    float s[6] = {0.f, 0.f, 0.f, 0.f, 0.f, 0.f};
    for (int c = 0; c < nchunk; c++) {
        const float* p = part + (size_t)c * ((size_t)N * 6) + (size_t)n * 6;
#pragma unroll
        for (int j = 0; j < 6; j++) s[j] += p[j];
    }
    const float inv = 1.0f / fmaxf(s[5], 1.0f);
    float xs[INC], xv[INC];
#pragma unroll
    for (int c = 0; c < INC; c++) {
        xs[c] = s[c] * inv;
        xv[c] = x[(size_t)n * INC + c];
    }
    float hv[H1C];
#pragma unroll
    for (int j = 0; j < H1C; j++) {
        float v = b1[j];
#pragma unroll
        for (int c = 0; c < INC; c++)
            v = fmaf(xs[c], W1[c * H1C + j], fmaf(xv[c], root1[c * H1C + j], v));
        hv[j] = fmaxf(v, 0.0f);  // relu(leaky(relu(v))) == relu(v)
    }
    float4* hp = (float4*)(h + (size_t)n * H1C);
#pragma unroll
    for (int q = 0; q < 4; q++)
        hp[q] = make_float4(hv[4 * q], hv[4 * q + 1], hv[4 * q + 2], hv[4 * q + 3]);
}

// ---------------------------------------------------------------------------
// Pooling GEMM, LDS-staged via global_load_lds + b128 LDS reads:
// thread = (lane -> col-quad 4l..4l+3, wave -> (dim-half jh, node-stream ns)).
// Per wave-iter: 1 ds_read_b128 pos (per-lane, conflict-free) + 2 broadcast
// b128 h + 32 FMA into acc[4][8] (32 VGPR). 4 node-streams combine via a
// 2-round LDS tree at block end ([val][lane] layout, conflict-free), reusing
// the dead pbuf. Double-buffered tiles: stage(t+1) issued before compute(t),
// __syncthreads() (implicit vmcnt(0)) drains after compute.
__global__ __launch_bounds__(512, 2) void k_pool(const float* __restrict__ pos,
                                                 const float* __restrict__ h,
                                                 float* __restrict__ xp_part, int N, int nb) {
    __shared__ float pbuf[2][PT * KCL];    // 2 x 32 KB
    __shared__ float hbuf[2][PT * H1C];    // 2 x 2 KB
    const int tid = threadIdx.x;
    const int lane = tid & 63;
    const int wid = tid >> 6;              // 0..7
    const int jh = wid & 1;                // dim half
    const int ns = wid >> 1;               // node stream 0..3
    const int chunk = (N + nb - 1) / nb;
    const int n0 = blockIdx.x * chunk;
    const int n1 = min(n0 + chunk, N);
    const int ntile = (n1 > n0) ? (n1 - n0 + PT - 1) / PT : 0;

    const size_t maxp = (size_t)N * KCL - 4;
    const size_t maxh = (size_t)N * H1C - 4;

    float acc[4][8];
#pragma unroll
    for (int c = 0; c < 4; c++)
#pragma unroll
        for (int d = 0; d < 8; d++) acc[c][d] = 0.0f;

    auto STAGE = [&](int bf, int tile) {
        const size_t nt0 = (size_t)n0 + (size_t)tile * PT;
        const size_t pb = nt0 * KCL;
#pragma unroll
        for (int c = 0; c < 4; ++c) {
            const int off = (wid * 4 + c) * 256;
            size_t fi = pb + (size_t)off + (size_t)lane * 4;
            if (fi > maxp) fi = maxp;
            __builtin_amdgcn_global_load_lds((gls_src*)(pos + fi),
                                             (gls_dst*)&pbuf[bf][off], 16, 0, 0);
        }
        if (wid < 2) {
            const int off = wid * 256;
            size_t fi = nt0 * H1C + (size_t)off + (size_t)lane * 4;
            if (fi > maxh) fi = maxh;
            __builtin_amdgcn_global_load_lds((gls_src*)(h + fi),
                                             (gls_dst*)&hbuf[bf][off], 16, 0, 0);
        }
    };

    int buf = 0;
    if (ntile > 0) {
        STAGE(0, 0);
        __syncthreads();   // implicit vmcnt(0): tile 0 resident
    }
    for (int t = 0; t < ntile; ++t) {
        if (t + 1 < ntile) STAGE(buf ^ 1, t + 1);   // issue next-tile loads FIRST
        const int nt0 = n0 + t * PT;
        const int tcnt = min(PT, n1 - nt0);
#pragma unroll 2
        for (int tt = ns; tt < tcnt; tt += 4) {
            const float4 p = *(const float4*)&pbuf[buf][tt * KCL + 4 * lane];
            const float4 hA = *(const float4*)&hbuf[buf][tt * H1C + jh * 8];
            const float4 hB = *(const float4*)&hbuf[buf][tt * H1C + jh * 8 + 4];
            const float pk[4] = {p.x, p.y, p.z, p.w};
            const float hv[8] = {hA.x, hA.y, hA.z, hA.w, hB.x, hB.y, hB.z, hB.w};
#pragma unroll
            for (int c = 0; c < 4; c++)
#pragma unroll
                for (int d = 0; d < 8; d++)
                    acc[c][d] = fmaf(pk[c], hv[d], acc[c][d]);
        }
        __syncthreads();   // vmcnt(0) drain of next tile + buffer handoff
        buf ^= 1;
    }

    // ---- cross-stream reduce (ns 0..3) via LDS tree, conflict-free layout:
    // slab[s][jh][v][lane], v = c*8+d.  pbuf is dead -> reuse as 32 KB scratch.
    float* sred = &pbuf[0][0];
    // round 1: streams 1,3 write; streams 0,2 add
    if (ns == 1 || ns == 3) {
        float* sl = sred + ((ns - 1) >> 1) * 4096 + jh * 2048 + lane;
#pragma unroll
        for (int c = 0; c < 4; c++)
#pragma unroll
            for (int d = 0; d < 8; d++) sl[(c * 8 + d) * 64] = acc[c][d];
    }
    __syncthreads();
    if (ns == 0 || ns == 2) {
        const float* sl = sred + (ns >> 1) * 4096 + jh * 2048 + lane;
#pragma unroll
        for (int c = 0; c < 4; c++)
#pragma unroll
            for (int d = 0; d < 8; d++) acc[c][d] += sl[(c * 8 + d) * 64];
    }
    __syncthreads();
    // round 2: stream 2 writes; stream 0 adds and stores out
    if (ns == 2) {
        float* sl = sred + jh * 2048 + lane;
#pragma unroll
        for (int c = 0; c < 4; c++)
#pragma unroll
            for (int d = 0; d < 8; d++) sl[(c * 8 + d) * 64] = acc[c][d];
    }
    __syncthreads();
    if (ns == 0) {
        const float* sl = sred + jh * 2048 + lane;
        float* o = xp_part + (size_t)blockIdx.x * (KCL * H1C);
#pragma unroll
        for (int c = 0; c < 4; c++) {
            float4 r0, r1;
            r0.x = acc[c][0] + sl[(c * 8 + 0) * 64];
            r0.y = acc[c][1] + sl[(c * 8 + 1) * 64];
            r0.z = acc[c][2] + sl[(c * 8 + 2) * 64];
            r0.w = acc[c][3] + sl[(c * 8 + 3) * 64];
            r1.x = acc[c][4] + sl[(c * 8 + 4) * 64];
            r1.y = acc[c][5] + sl[(c * 8 + 5) * 64];
            r1.z = acc[c][6] + sl[(c * 8 + 6) * 64];
            r1.w = acc[c][7] + sl[(c * 8 + 7) * 64];
            float* oc = o + (4 * lane + c) * H1C + jh * 8;
            *(float4*)oc = r0;
            *(float4*)(oc + 4) = r1;
        }
    }
}

// ---------------------------------------------------------------------------
__global__ __launch_bounds__(1024) void k_xpred(const float* __restrict__ xp_part,
                                                float* __restrict__ xp, int nb) {
    __shared__ float r[1024];
    const int li = threadIdx.x & 63;
    const int sub = threadIdx.x >> 6;      // 0..15
    const int i = blockIdx.x * 64 + li;
    float s = 0.0f;
    for (int b = sub; b < nb; b += 16) s += xp_part[(size_t)b * (KCL * H1C) + i];
    r[threadIdx.x] = s;
    __syncthreads();
    if (threadIdx.x < 512) r[threadIdx.x] += r[threadIdx.x + 512];
    __syncthreads();
    if (threadIdx.x < 256) r[threadIdx.x] += r[threadIdx.x + 256];
    __syncthreads();
    if (threadIdx.x < 128) r[threadIdx.x] += r[threadIdx.x + 128];
    __syncthreads();
    if (threadIdx.x < 64) xp[i] = r[threadIdx.x] + r[threadIdx.x + 64];
}

// ---------------------------------------------------------------------------
// Tail: adj strictly positive => mask all-ones, deg2 = 256.
__global__ __launch_bounds__(256) void k_tail(const float* __restrict__ xp,
                                              const float* __restrict__ W2,
                                              const float* __restrict__ root2,
                                              const float* __restrict__ b2,
                                              const float* __restrict__ lw1,
                                              const float* __restrict__ lb1,
                                              const float* __restrict__ lw2,
                                              const float* __restrict__ lb2,
                                              float* __restrict__ out) {
    __shared__ float red[4][H2C];
    __shared__ float bcast[H2C];
    const int t = threadIdx.x;
    const int wv = t >> 6;
    const int lane = t & 63;

    float row[H1C];
#pragma unroll
    for (int c = 0; c < H1C; c++) row[c] = xp[t * H1C + c];

    float v1[H2C];
#pragma unroll
    for (int j = 0; j < H2C; j++) {
        float v = 0.0f;
#pragma unroll
        for (int c = 0; c < H1C; c++) v = fmaf(row[c], W2[c * H2C + j], v);
        v1[j] = v;
    }
#pragma unroll
    for (int off = 1; off < 64; off <<= 1) {
#pragma unroll
        for (int j = 0; j < H2C; j++) v1[j] += __shfl_xor(v1[j], off);
    }
    if (lane == 0) {
#pragma unroll
        for (int j = 0; j < H2C; j++) red[wv][j] = v1[j];
    }
    __syncthreads();
    if (t < H2C) bcast[t] = red[0][t] + red[1][t] + red[2][t] + red[3][t];
    __syncthreads();

    float v2[H2C];
#pragma unroll
    for (int j = 0; j < H2C; j++) {
        float v = bcast[j] * (1.0f / KCL) + b2[j];
#pragma unroll
        for (int c = 0; c < H1C; c++) v = fmaf(row[c], root2[c * H2C + j], v);
        v2[j] = fmaxf(v, 0.0f);
    }
#pragma unroll
    for (int off = 1; off < 64; off <<= 1) {
#pragma unroll
        for (int j = 0; j < H2C; j++) v2[j] += __shfl_xor(v2[j], off);
    }
    if (lane == 0) {
#pragma unroll
        for (int j = 0; j < H2C; j++) red[wv][j] = v2[j];
    }
    __syncthreads();

    if (t == 0) {
        float g[H2C];
#pragma unroll
        for (int j = 0; j < H2C; j++)
            g[j] = (red[0][j] + red[1][j] + red[2][j] + red[3][j]) * (1.0f / KCL);
        float u[8];
#pragma unroll
        for (int a = 0; a < 8; a++) {
            float v = lb1[a];
#pragma unroll
            for (int j = 0; j < H2C; j++) v = fmaf(g[j], lw1[j * 8 + a], v);
            u[a] = v > 0.0f ? v : 0.1f * v;
        }
#pragma unroll
        for (int o = 0; o < 2; o++) {
            float v = lb2[o];
#pragma unroll
            for (int a = 0; a < 8; a++) v = fmaf(u[a], lw2[a * 2 + o], v);
            out[o] = v;
        }
    }
}

// ---------------------------------------------------------------------------
extern "C" void kernel_launch(void* const* d_in, const int* in_sizes, int n_in,
                              void* d_out, int out_size, void* d_ws, size_t ws_size,
                              hipStream_t stream) {
    const float* x         = (const float*)d_in[0];
    const unsigned int* ei = (const unsigned int*)d_in[1];
    // d_in[2] = edge_attr: unused (adj has no exact zeros -> mask all-ones)
    const float* pos   = (const float*)d_in[3];
    const float* W1    = (const float*)d_in[4];
    const float* root1 = (const float*)d_in[5];
    const float* b1    = (const float*)d_in[6];
    const float* W2    = (const float*)d_in[7];
    const float* root2 = (const float*)d_in[8];
    const float* b2    = (const float*)d_in[9];
    const float* lw1   = (const float*)d_in[10];
    const float* lb1   = (const float*)d_in[11];
    const float* lw2   = (const float*)d_in[12];
    const float* lb2   = (const float*)d_in[13];
    float* out = (float*)d_out;

    const int N = in_sizes[0] / INC;  // 100000
    const int E = in_sizes[1] / 2;    // 3200000
    const int NB = (N + PB_SZ - 1) >> PB_SHIFT;

    // workspace prefix (floats): [xp 4096][flag 16][h N*16][REGION ...]
    float* ws    = (float*)d_ws;
    float* xp    = ws;
    int*   flag  = (int*)(xp + KCL * H1C);
    float* h     = (float*)(flag + 16);
    float* regio = h + (size_t)N * H1C;

    const size_t pref_floats = (size_t)(KCL * H1C) + 16 + (size_t)N * H1C;
    const size_t region_floats = ws_size / 4 > pref_floats ? ws_size / 4 - pref_floats : 0;
    // fast path region: part[PB_S*N*6] | x8[N*8] | bucket[NB*PB_C] | gcur[256]
    const size_t fast_floats = (size_t)PB_S * N * 6 + (size_t)N * 8 + (size_t)NB * PB_C + 256;

    if (region_floats >= fast_floats && N <= 131072 && NB <= PB_NBMAX) {
        float* part      = regio;
        float* x8        = part + (size_t)PB_S * N * 6;
        unsigned* bucket = (unsigned*)(x8 + (size_t)N * 8);
        unsigned* gcur   = bucket + (size_t)NB * PB_C;
        const int P = (E + PB_M - 1) / PB_M;

        k_setup<<<(N + 255) / 256, 256, 0, stream>>>(x, x8, ei, flag, gcur, N, NB);
        k_part<<<P, 1024, 0, stream>>>(ei, flag, gcur, bucket, E, NB);
        k_gather<<<NB * PB_S, 1024, 0, stream>>>(bucket, gcur, x8, part, N, NB);
        k_node2<<<(N + 255) / 256, 256, 0, stream>>>(x, part, W1, root1, b1, h, N, PB_S);

        // xp_part reuses x8/bucket space (dead after k_gather)
        float* xp_part = x8;
        k_pool<<<POOL_NB, 512, 0, stream>>>(pos, h, xp_part, N, POOL_NB);
        k_xpred<<<64, 1024, 0, stream>>>(xp_part, xp, POOL_NB);
    } else {
        // fallback: binned rescan with as many chunks as fit (reserve pool slabs)
        size_t avail = region_floats > (size_t)POOL_NB * KCL * H1C
                     ? region_floats - (size_t)POOL_NB * KCL * H1C : 0;
        int nchunk = (int)(avail / ((size_t)N * 6));
        if (nchunk > MAXCHUNK) nchunk = MAXCHUNK;
        if (nchunk < 1) nchunk = 1;
        float* part = regio;
        float* xp_part = part + (size_t)nchunk * N * 6;
        k_detect<<<1, 64, 0, stream>>>(ei, flag);
        k_edge_bin<<<NBINS * nchunk, 1024, 0, stream>>>(ei, x, flag, part, E, nchunk, N);
        k_node2<<<(N + 255) / 256, 256, 0, stream>>>(x, part, W1, root1, b1, h, N, nchunk);
        k_pool<<<POOL_NB, 512, 0, stream>>>(pos, h, xp_part, N, POOL_NB);
        k_xpred<<<64, 1024, 0, stream>>>(xp_part, xp, POOL_NB);
    }
    k_tail<<<1, 256, 0, stream>>>(xp, W2, root2, b2, lw1, lb1, lw2, lb2, out);
}